// Round 4
// baseline (223.646 us; speedup 1.0000x reference)
//
#include <hip/hip_runtime.h>

typedef unsigned short u16;
typedef __attribute__((ext_vector_type(4))) float f32x4;
typedef __attribute__((ext_vector_type(8))) __bf16 bf16x8;
typedef __attribute__((ext_vector_type(4))) __bf16 bf16x4;
typedef __attribute__((ext_vector_type(4))) unsigned short u16x4;
typedef __attribute__((ext_vector_type(8))) unsigned short u16x8;

// round-to-nearest-even fp32 -> bf16 (used in epilogues / converts)
static __device__ __forceinline__ u16 f2bf(float f) {
    union { float f; unsigned u; } v; v.f = f;
    unsigned r = v.u + 0x7FFFu + ((v.u >> 16) & 1u);
    return (u16)(r >> 16);
}

// v_exp_f32: D = 2^x
static __device__ __forceinline__ float exp2f_fast(float x) {
    float r; asm("v_exp_f32 %0, %1" : "=v"(r) : "v"(x)); return r;
}

// async global->LDS, 16 bytes per lane (dest must be uniform base + lane*16)
static __device__ __forceinline__ void gload16(const u16* g, u16* l) {
    __builtin_amdgcn_global_load_lds(
        (const __attribute__((address_space(1))) unsigned int*)g,
        (__attribute__((address_space(3))) unsigned int*)l, 16, 0, 0);
}

// fused counted-wait + raw barrier (no compiler vmcnt(0)-drain semantics beyond what we ask)
#define WAIT_BAR() asm volatile("s_waitcnt vmcnt(0)\n\ts_barrier" ::: "memory")

// swizzled element offset in a [rows][64] u16 tile (128B rows, XOR 16B-chunk by row&7)
#define SWZ64(row, ec) (((row) * 64) + ((((ec) ^ ((row) & 7))) << 3))

// ---------------- fp32 -> bf16 convert (4 elems/thread) ----------------
__global__ __launch_bounds__(256) void k_cvt(const float* __restrict__ in, u16* __restrict__ out) {
    size_t i = (size_t)blockIdx.x * 256 + threadIdx.x;
    float4 v = ((const float4*)in)[i];
    u16x4 o; o[0] = f2bf(v.x); o[1] = f2bf(v.y); o[2] = f2bf(v.z); o[3] = f2bf(v.w);
    *(u16x4*)(out + i * 4) = o;
}

// ---------------- 4x W [K=1024][N=1024] fp32 -> Wt [N][K] bf16 (scaled), one launch ----------------
__global__ __launch_bounds__(256) void k_wtrans4(
    const float* __restrict__ W0, const float* __restrict__ W1,
    const float* __restrict__ W2, const float* __restrict__ W3,
    u16* __restrict__ T0, u16* __restrict__ T1, u16* __restrict__ T2, u16* __restrict__ T3,
    float s0) {
    const float* W; u16* Tt; float sc;
    switch (blockIdx.z) {
        case 0:  W = W0; Tt = T0; sc = s0;  break;
        case 1:  W = W1; Tt = T1; sc = 1.f; break;
        case 2:  W = W2; Tt = T2; sc = 1.f; break;
        default: W = W3; Tt = T3; sc = 1.f; break;
    }
    __shared__ float tile[32][33];
    int n0 = blockIdx.x * 32, k0 = blockIdx.y * 32;
    int tid = threadIdx.x;
    int r = tid >> 3, c = (tid & 7) * 4;
    float4 v = *(const float4*)(W + (size_t)(k0 + r) * 1024 + n0 + c);
    tile[r][c] = v.x; tile[r][c + 1] = v.y; tile[r][c + 2] = v.z; tile[r][c + 3] = v.w;
    __syncthreads();
    u16x4 o;
    o[0] = f2bf(tile[c][r] * sc);
    o[1] = f2bf(tile[c + 1][r] * sc);
    o[2] = f2bf(tile[c + 2][r] * sc);
    o[3] = f2bf(tile[c + 3][r] * sc);
    *(u16x4*)(Tt + (size_t)(n0 + r) * 1024 + k0 + c) = o;
}

// ---------------- bf16 GEMM: C[M][N] = A[M][1024] * Bt[N][1024]^T + bias ----------------
// 128x128 tile, BK=32, 4 waves (2x2 of 64x64), 4x4 frags/wave.
// 2-phase double-buffered LDS: stage tile t+1 before computing tile t; single fused
// vmcnt(0)+s_barrier per K-step (stage latency hides under compute). Static dbuf indices.
static __device__ __forceinline__ void gemm_step(const u16* As, const u16* Bs,
                                                 int wm, int wn, int fr, int f8,
                                                 f32x4 acc[4][4]) {
    bf16x8 af[4], bf[4];
#pragma unroll
    for (int mt = 0; mt < 4; ++mt) af[mt] = *(const bf16x8*)(&As[(wm + mt * 16 + fr) * 32 + f8]);
#pragma unroll
    for (int nt = 0; nt < 4; ++nt) bf[nt] = *(const bf16x8*)(&Bs[(wn + nt * 16 + fr) * 32 + f8]);
#pragma unroll
    for (int mt = 0; mt < 4; ++mt)
#pragma unroll
        for (int nt = 0; nt < 4; ++nt)
            acc[mt][nt] = __builtin_amdgcn_mfma_f32_16x16x32_bf16(af[mt], bf[nt], acc[mt][nt], 0, 0, 0);
}

__global__ __launch_bounds__(256) void k_gemm(const u16* __restrict__ A, const u16* __restrict__ Bt,
                                              const float* __restrict__ bias, float bias_scale,
                                              u16* __restrict__ obf, float* __restrict__ of32,
                                              int ldc, int bias_row) {
    __shared__ u16 As0[128 * 32], Bs0[128 * 32];
    __shared__ u16 As1[128 * 32], Bs1[128 * 32];
    const int tid = threadIdx.x;
    const int l = tid & 63, w = tid >> 6;
    const int wm = (w >> 1) * 64, wn = (w & 1) * 64;
    const size_t m0 = (size_t)blockIdx.y * 128, n0 = (size_t)blockIdx.x * 128;
    const int fr = l & 15, f8 = (l >> 4) * 8, f4 = (l >> 4) * 4;
    // staging geometry: 1KB chunk j holds rows j*16..j*16+15; lane l -> row j*16+(l>>2), col (l&3)*8
    const int j0 = w * 2;
    const int srow0 = j0 * 16 + (l >> 2), srow1 = srow0 + 16;
    const int scol = (l & 3) * 8;
    const u16* Ag0 = A + (m0 + srow0) * 1024 + scol;
    const u16* Ag1 = A + (m0 + srow1) * 1024 + scol;
    const u16* Bg0 = Bt + (n0 + srow0) * 1024 + scol;
    const u16* Bg1 = Bt + (n0 + srow1) * 1024 + scol;
    const int lo0 = j0 * 512 + l * 8, lo1 = (j0 + 1) * 512 + l * 8;

#define GSTAGE(ASB, BSB, kt)            \
    gload16(Ag0 + (kt), (ASB) + lo0);   \
    gload16(Ag1 + (kt), (ASB) + lo1);   \
    gload16(Bg0 + (kt), (BSB) + lo0);   \
    gload16(Bg1 + (kt), (BSB) + lo1)

    f32x4 acc[4][4] = {};
    GSTAGE(As0, Bs0, 0);
    WAIT_BAR();
    for (int kt = 0; kt < 1024; kt += 64) {
        if (kt + 32 < 1024) { GSTAGE(As1, Bs1, kt + 32); }
        gemm_step(As0, Bs0, wm, wn, fr, f8, acc);
        WAIT_BAR();
        if (kt + 64 < 1024) { GSTAGE(As0, Bs0, kt + 64); }
        gemm_step(As1, Bs1, wm, wn, fr, f8, acc);
        WAIT_BAR();
    }
#undef GSTAGE
    // epilogue: C/D layout col=lane&15, row=(lane>>4)*4+r  [HW-verified]
#pragma unroll
    for (int mt = 0; mt < 4; ++mt) {
        float rb_[4];
#pragma unroll
        for (int r = 0; r < 4; ++r)
            rb_[r] = bias_row ? bias[m0 + wm + mt * 16 + f4 + r] * bias_scale : 0.f;
#pragma unroll
        for (int nt = 0; nt < 4; ++nt) {
            const size_t col = n0 + wn + nt * 16 + fr;
            const float cb = bias_row ? 0.f : bias[col] * bias_scale;
#pragma unroll
            for (int r = 0; r < 4; ++r) {
                const size_t row = m0 + wm + mt * 16 + f4 + r;
                const float vv = acc[mt][nt][r] + cb + rb_[r];
                if (of32) of32[row * (size_t)ldc + col] = vv;
                else      obf[row * (size_t)ldc + col] = f2bf(vv);
            }
        }
    }
}

// ---------------- flash attention ----------------
static __device__ __forceinline__ void softmax_grp(const f32x4 s[4], f32x4 o[4],
                                                   float& m, float& lsum, bf16x4 p[4]) {
    float tmax = s[0][0];
#pragma unroll
    for (int nt = 0; nt < 4; ++nt)
#pragma unroll
        for (int r = 0; r < 4; ++r) tmax = fmaxf(tmax, s[nt][r]);
    tmax = fmaxf(tmax, __shfl_xor(tmax, 16, 64));
    tmax = fmaxf(tmax, __shfl_xor(tmax, 32, 64));
    float ps = 0.f;
    if (__any(tmax > 11.0f)) {            // T13 defer-rescale: rare with this data
        const float d = fmaxf(tmax, 0.f);
        const float fac = exp2f_fast(-d);
        m += d; lsum *= fac;
#pragma unroll
        for (int mt = 0; mt < 4; ++mt)
#pragma unroll
            for (int r = 0; r < 4; ++r) o[mt][r] *= fac;
#pragma unroll
        for (int nt = 0; nt < 4; ++nt)
#pragma unroll
            for (int r = 0; r < 4; ++r) {
                const float pp = exp2f_fast(s[nt][r] - d);
                ps += pp; p[nt][r] = (__bf16)pp;
            }
    } else {
#pragma unroll
        for (int nt = 0; nt < 4; ++nt)
#pragma unroll
            for (int r = 0; r < 4; ++r) {
                const float pp = exp2f_fast(s[nt][r]);
                ps += pp; p[nt][r] = (__bf16)pp;
            }
    }
    ps += __shfl_xor(ps, 16, 64);
    ps += __shfl_xor(ps, 32, 64);
    lsum += ps;
}

static __device__ __forceinline__ void flash_tile(const u16* Ks, const u16* Vs,
                                                  int fr, int gg,
                                                  bf16x8 qA0, bf16x8 qA1, bf16x8 qB0, bf16x8 qB1,
                                                  f32x4 oA[4], f32x4 oB[4],
                                                  float& mA, float& lA, float& mB, float& lB) {
    // S^T = mfma(K, Q) with C-init = -m (log2 domain); lane q = fr, k = nt*16+gg*4+r
    f32x4 sA[4], sB[4];
    __builtin_amdgcn_s_setprio(1);
#pragma unroll
    for (int nt = 0; nt < 4; ++nt) {
        const int rk = nt * 16 + fr;
        const bf16x8 kf0 = *(const bf16x8*)(&Ks[SWZ64(rk, gg)]);
        const bf16x8 kf1 = *(const bf16x8*)(&Ks[SWZ64(rk, gg + 4)]);
        f32x4 z = {-mA, -mA, -mA, -mA};
        z = __builtin_amdgcn_mfma_f32_16x16x32_bf16(kf0, qA0, z, 0, 0, 0);
        z = __builtin_amdgcn_mfma_f32_16x16x32_bf16(kf1, qA1, z, 0, 0, 0);
        sA[nt] = z;
        f32x4 y = {-mB, -mB, -mB, -mB};
        y = __builtin_amdgcn_mfma_f32_16x16x32_bf16(kf0, qB0, y, 0, 0, 0);
        y = __builtin_amdgcn_mfma_f32_16x16x32_bf16(kf1, qB1, y, 0, 0, 0);
        sB[nt] = y;
    }
    __builtin_amdgcn_s_setprio(0);
    bf16x4 pA[4], pB[4];
    softmax_grp(sA, oA, mA, lA, pA);
    softmax_grp(sB, oB, mB, lB, pB);
    // B-fragments straight from registers (k-permutation invariance)
    const bf16x8 BA0 = __builtin_shufflevector(pA[0], pA[1], 0, 1, 2, 3, 4, 5, 6, 7);
    const bf16x8 BA1 = __builtin_shufflevector(pA[2], pA[3], 0, 1, 2, 3, 4, 5, 6, 7);
    const bf16x8 BB0 = __builtin_shufflevector(pB[0], pB[1], 0, 1, 2, 3, 4, 5, 6, 7);
    const bf16x8 BB1 = __builtin_shufflevector(pB[2], pB[3], 0, 1, 2, 3, 4, 5, 6, 7);
    // PV: A-frag reg j = V^T[hd][(j>>2)*16 + gg*4 + (j&3)] (matching permuted k-order)
    const int e0 = gg >> 1, hf = (gg & 1) * 4;
    __builtin_amdgcn_s_setprio(1);
#pragma unroll
    for (int mt = 0; mt < 4; ++mt) {
        const int rv = mt * 16 + fr;
        const int rs = rv & 7, rb = rv * 64;
        const bf16x4 v0 = *(const bf16x4*)(&Vs[rb + (((e0    ) ^ rs) << 3) + hf]);
        const bf16x4 v1 = *(const bf16x4*)(&Vs[rb + (((e0 + 2) ^ rs) << 3) + hf]);
        const bf16x4 v2 = *(const bf16x4*)(&Vs[rb + (((e0 + 4) ^ rs) << 3) + hf]);
        const bf16x4 v3 = *(const bf16x4*)(&Vs[rb + (((e0 + 6) ^ rs) << 3) + hf]);
        const bf16x8 vk0 = __builtin_shufflevector(v0, v1, 0, 1, 2, 3, 4, 5, 6, 7);
        const bf16x8 vk1 = __builtin_shufflevector(v2, v3, 0, 1, 2, 3, 4, 5, 6, 7);
        oA[mt] = __builtin_amdgcn_mfma_f32_16x16x32_bf16(vk0, BA0, oA[mt], 0, 0, 0);
        oA[mt] = __builtin_amdgcn_mfma_f32_16x16x32_bf16(vk1, BA1, oA[mt], 0, 0, 0);
        oB[mt] = __builtin_amdgcn_mfma_f32_16x16x32_bf16(vk0, BB0, oB[mt], 0, 0, 0);
        oB[mt] = __builtin_amdgcn_mfma_f32_16x16x32_bf16(vk1, BB1, oB[mt], 0, 0, 0);
    }
    __builtin_amdgcn_s_setprio(0);
}

// 1D grid 1024 blocks (XCD-bijective swizzle -> K/V L2-resident). 4 waves, 32 q-rows/wave
// (groups A/B). V read directly from Vt2[n_global][t_global] (ld=8192) - no vtrans kernel.
// 2-phase double-buffered K/V staging, fused vmcnt(0)+s_barrier per tile.
__global__ __launch_bounds__(256, 4) void k_flash(const u16* __restrict__ Q, const u16* __restrict__ K,
                                                  const u16* __restrict__ Vt2, u16* __restrict__ O) {
    __shared__ u16 Ks0[64 * 64], Vs0[64 * 64];
    __shared__ u16 Ks1[64 * 64], Vs1[64 * 64];
    const int tid = threadIdx.x;
    const int l = tid & 63, w = tid >> 6;
    const int id = blockIdx.x;
    const int swz = (id & 7) * 128 + (id >> 3);      // bijective XCD swizzle (1024 % 8 == 0)
    const int bh = swz >> 3, qt = swz & 7;
    const int b = bh >> 4, h = bh & 15;
    const int qw = qt * 128 + w * 32;
    const int fr = l & 15, gg = l >> 4, f4 = gg * 4, f8 = gg * 8;

    // Q fragments (SCALE*LOG2E folded into Wq/bq)
    const u16* qpA = Q + ((size_t)(b * 1024 + qw + fr)) * 1024 + h * 64 + f8;
    const u16* qpB = qpA + 16 * 1024;
    const bf16x8 qA0 = *(const bf16x8*)qpA;
    const bf16x8 qA1 = *(const bf16x8*)(qpA + 32);
    const bf16x8 qB0 = *(const bf16x8*)qpB;
    const bf16x8 qB1 = *(const bf16x8*)(qpB + 32);

    // staging: chunk j (0..7) = rows j*8..j*8+7; lane l -> row j*8+(l>>3),
    // source 16B-chunk (l&7)^(l>>3) (pre-swizzled source, linear LDS dest)
    const int jj0 = w * 2, jj1 = w * 2 + 1;
    const int sr0 = jj0 * 8 + (l >> 3), sr1 = jj1 * 8 + (l >> 3);
    const int sc = ((l & 7) ^ (l >> 3)) * 8;
    const u16* kg0 = K + ((size_t)(b * 1024 + sr0)) * 1024 + h * 64 + sc;
    const u16* kg1 = K + ((size_t)(b * 1024 + sr1)) * 1024 + h * 64 + sc;
    const u16* vg0 = Vt2 + ((size_t)(h * 64 + sr0)) * 8192 + b * 1024 + sc;
    const u16* vg1 = Vt2 + ((size_t)(h * 64 + sr1)) * 8192 + b * 1024 + sc;
    const int lk0 = jj0 * 512 + l * 8, lk1 = jj1 * 512 + l * 8;

#define FSTAGE(KSB, VSB, kt)                            \
    gload16(kg0 + (size_t)(kt) * 1024, (KSB) + lk0);    \
    gload16(kg1 + (size_t)(kt) * 1024, (KSB) + lk1);    \
    gload16(vg0 + (kt), (VSB) + lk0);                   \
    gload16(vg1 + (kt), (VSB) + lk1)

    f32x4 oA[4] = {}, oB[4] = {};
    float mA = 0.f, lA = 0.f, mB = 0.f, lB = 0.f;

    FSTAGE(Ks0, Vs0, 0);
    WAIT_BAR();
    for (int kt0 = 0; kt0 < 1024; kt0 += 128) {
        if (kt0 + 64 < 1024) { FSTAGE(Ks1, Vs1, kt0 + 64); }
        flash_tile(Ks0, Vs0, fr, gg, qA0, qA1, qB0, qB1, oA, oB, mA, lA, mB, lB);
        WAIT_BAR();
        if (kt0 + 128 < 1024) { FSTAGE(Ks0, Vs0, kt0 + 128); }
        flash_tile(Ks1, Vs1, fr, gg, qA0, qA1, qB0, qB1, oA, oB, mA, lA, mB, lB);
        WAIT_BAR();
    }
#undef FSTAGE
    // epilogue: O[t][h*64 + mt*16 + f4 + r]
    const float ivA = 1.0f / lA, ivB = 1.0f / lB;
    u16* opA = O + ((size_t)(b * 1024 + qw + fr)) * 1024 + h * 64;
    u16* opB = opA + 16 * 1024;
#pragma unroll
    for (int mt = 0; mt < 4; ++mt) {
        u16x4 oa, ob;
#pragma unroll
        for (int r = 0; r < 4; ++r) { oa[r] = f2bf(oA[mt][r] * ivA); ob[r] = f2bf(oB[mt][r] * ivB); }
        *(u16x4*)(opA + mt * 16 + f4) = oa;
        *(u16x4*)(opB + mt * 16 + f4) = ob;
    }
}

extern "C" void kernel_launch(void* const* d_in, const int* in_sizes, int n_in,
                              void* d_out, int out_size, void* d_ws, size_t ws_size,
                              hipStream_t stream) {
    (void)in_sizes; (void)n_in; (void)out_size; (void)ws_size;
    const float* hs = (const float*)d_in[0];
    const float* Wq = (const float*)d_in[1];
    const float* bq = (const float*)d_in[2];
    const float* Wk = (const float*)d_in[3];
    const float* bk = (const float*)d_in[4];
    const float* Wv = (const float*)d_in[5];
    const float* bv = (const float*)d_in[6];
    const float* Wo = (const float*)d_in[7];
    const float* bo = (const float*)d_in[8];
    float* out = (float*)d_out;
    char* ws = (char*)d_ws;
    const size_t MB = 1024ull * 1024ull;
    u16* Xb  = (u16*)(ws);            // 16 MB (dead after last GEMM use; reused as attn output Ob)
    u16* Wqt = (u16*)(ws + 16 * MB);  // 2 MB each
    u16* Wkt = (u16*)(ws + 18 * MB);
    u16* Wvt = (u16*)(ws + 20 * MB);
    u16* Wot = (u16*)(ws + 22 * MB);
    u16* Qb  = (u16*)(ws + 24 * MB);  // 16 MB
    u16* Kb  = (u16*)(ws + 40 * MB);  // 16 MB
    u16* Vt2 = (u16*)(ws + 56 * MB);  // 16 MB: V^T[n_global][t_global], ld=8192 -> 72 MB total
    u16* Ob  = Xb;

    // HD^-0.5 * log2(e) folded into Wq and bq (softmax runs in log2 domain)
    const float SCALE_Q = 0.125f * 1.4426950408889634f;

    k_cvt<<<dim3(8192), dim3(256), 0, stream>>>(hs, Xb);
    k_wtrans4<<<dim3(32, 32, 4), dim3(256), 0, stream>>>(Wq, Wk, Wv, Wo, Wqt, Wkt, Wvt, Wot, SCALE_Q);
    k_gemm<<<dim3(8, 64), dim3(256), 0, stream>>>(Xb, Wqt, bq, SCALE_Q, Qb, nullptr, 1024, 0);
    k_gemm<<<dim3(8, 64), dim3(256), 0, stream>>>(Xb, Wkt, bk, 1.0f, Kb, nullptr, 1024, 0);
    // V^T = Wv^T * X^T : A = Wvt [n][k], Bt = Xb [t][k], C = Vt2 [n][t] (ld 8192), bias per row
    k_gemm<<<dim3(64, 8), dim3(256), 0, stream>>>(Wvt, Xb, bv, 1.0f, Vt2, nullptr, 8192, 1);
    k_flash<<<dim3(1024), dim3(256), 0, stream>>>(Qb, Kb, Vt2, Ob);
    k_gemm<<<dim3(8, 64), dim3(256), 0, stream>>>(Ob, Wot, bo, 1.0f, nullptr, out, 1024, 0);
}

// Round 5
// 204.377 us; speedup vs baseline: 1.0943x; 1.0943x over previous
//
#include <hip/hip_runtime.h>

typedef unsigned short u16;
typedef __attribute__((ext_vector_type(4))) float f32x4;
typedef __attribute__((ext_vector_type(8))) __bf16 bf16x8;
typedef __attribute__((ext_vector_type(4))) __bf16 bf16x4;
typedef __attribute__((ext_vector_type(4))) unsigned short u16x4;
typedef __attribute__((ext_vector_type(8))) unsigned short u16x8;

// round-to-nearest-even fp32 -> bf16 (used in epilogues / converts)
static __device__ __forceinline__ u16 f2bf(float f) {
    union { float f; unsigned u; } v; v.f = f;
    unsigned r = v.u + 0x7FFFu + ((v.u >> 16) & 1u);
    return (u16)(r >> 16);
}

// v_exp_f32: D = 2^x
static __device__ __forceinline__ float exp2f_fast(float x) {
    float r; asm("v_exp_f32 %0, %1" : "=v"(r) : "v"(x)); return r;
}

// async global->LDS, 16 bytes per lane (dest must be uniform base + lane*16)
static __device__ __forceinline__ void gload16(const u16* g, u16* l) {
    __builtin_amdgcn_global_load_lds(
        (const __attribute__((address_space(1))) unsigned int*)g,
        (__attribute__((address_space(3))) unsigned int*)l, 16, 0, 0);
}

// fused counted-wait + raw barrier (no compiler vmcnt(0)-drain semantics beyond what we ask)
#define WAIT_BAR() asm volatile("s_waitcnt vmcnt(0)\n\ts_barrier" ::: "memory")

// swizzled element offset in a [rows][64] u16 tile (128B rows, XOR 16B-chunk by row&7)
#define SWZ64(row, ec) (((row) * 64) + ((((ec) ^ ((row) & 7))) << 3))

// ---------------- fp32 -> bf16 convert (4 elems/thread) ----------------
__global__ __launch_bounds__(256) void k_cvt(const float* __restrict__ in, u16* __restrict__ out) {
    size_t i = (size_t)blockIdx.x * 256 + threadIdx.x;
    float4 v = ((const float4*)in)[i];
    u16x4 o; o[0] = f2bf(v.x); o[1] = f2bf(v.y); o[2] = f2bf(v.z); o[3] = f2bf(v.w);
    *(u16x4*)(out + i * 4) = o;
}

// ---------------- 4x W [K=1024][N=1024] fp32 -> Wt [N][K] bf16 (scaled), one launch ----------------
__global__ __launch_bounds__(256) void k_wtrans4(
    const float* __restrict__ W0, const float* __restrict__ W1,
    const float* __restrict__ W2, const float* __restrict__ W3,
    u16* __restrict__ T0, u16* __restrict__ T1, u16* __restrict__ T2, u16* __restrict__ T3,
    float s0) {
    const float* W; u16* Tt; float sc;
    switch (blockIdx.z) {
        case 0:  W = W0; Tt = T0; sc = s0;  break;
        case 1:  W = W1; Tt = T1; sc = 1.f; break;
        case 2:  W = W2; Tt = T2; sc = 1.f; break;
        default: W = W3; Tt = T3; sc = 1.f; break;
    }
    __shared__ float tile[32][33];
    int n0 = blockIdx.x * 32, k0 = blockIdx.y * 32;
    int tid = threadIdx.x;
    int r = tid >> 3, c = (tid & 7) * 4;
    float4 v = *(const float4*)(W + (size_t)(k0 + r) * 1024 + n0 + c);
    tile[r][c] = v.x; tile[r][c + 1] = v.y; tile[r][c + 2] = v.z; tile[r][c + 3] = v.w;
    __syncthreads();
    u16x4 o;
    o[0] = f2bf(tile[c][r] * sc);
    o[1] = f2bf(tile[c + 1][r] * sc);
    o[2] = f2bf(tile[c + 2][r] * sc);
    o[3] = f2bf(tile[c + 3][r] * sc);
    *(u16x4*)(Tt + (size_t)(n0 + r) * 1024 + k0 + c) = o;
}

// ---------------- bf16 GEMM: C[M][N] = A[M][1024] * Bt[N][1024]^T + bias ----------------
// 128x128 tile, BK=32, 4 waves (2x2 of 64x64), 4x4 frags/wave.
// 2-phase double-buffered LDS: stage tile t+1 before computing tile t; single fused
// vmcnt(0)+s_barrier per K-step (stage latency hides under compute). Static dbuf indices.
static __device__ __forceinline__ void gemm_step(const u16* As, const u16* Bs,
                                                 int wm, int wn, int fr, int f8,
                                                 f32x4 acc[4][4]) {
    bf16x8 af[4], bf[4];
#pragma unroll
    for (int mt = 0; mt < 4; ++mt) af[mt] = *(const bf16x8*)(&As[(wm + mt * 16 + fr) * 32 + f8]);
#pragma unroll
    for (int nt = 0; nt < 4; ++nt) bf[nt] = *(const bf16x8*)(&Bs[(wn + nt * 16 + fr) * 32 + f8]);
#pragma unroll
    for (int mt = 0; mt < 4; ++mt)
#pragma unroll
        for (int nt = 0; nt < 4; ++nt)
            acc[mt][nt] = __builtin_amdgcn_mfma_f32_16x16x32_bf16(af[mt], bf[nt], acc[mt][nt], 0, 0, 0);
}

__global__ __launch_bounds__(256) void k_gemm(const u16* __restrict__ A, const u16* __restrict__ Bt,
                                              const float* __restrict__ bias, float bias_scale,
                                              u16* __restrict__ obf, float* __restrict__ of32,
                                              int ldc, int bias_row) {
    __shared__ u16 As0[128 * 32], Bs0[128 * 32];
    __shared__ u16 As1[128 * 32], Bs1[128 * 32];
    const int tid = threadIdx.x;
    const int l = tid & 63, w = tid >> 6;
    const int wm = (w >> 1) * 64, wn = (w & 1) * 64;
    const size_t m0 = (size_t)blockIdx.y * 128, n0 = (size_t)blockIdx.x * 128;
    const int fr = l & 15, f8 = (l >> 4) * 8, f4 = (l >> 4) * 4;
    // staging geometry: 1KB chunk j holds rows j*16..j*16+15; lane l -> row j*16+(l>>2), col (l&3)*8
    const int j0 = w * 2;
    const int srow0 = j0 * 16 + (l >> 2), srow1 = srow0 + 16;
    const int scol = (l & 3) * 8;
    const u16* Ag0 = A + (m0 + srow0) * 1024 + scol;
    const u16* Ag1 = A + (m0 + srow1) * 1024 + scol;
    const u16* Bg0 = Bt + (n0 + srow0) * 1024 + scol;
    const u16* Bg1 = Bt + (n0 + srow1) * 1024 + scol;
    const int lo0 = j0 * 512 + l * 8, lo1 = (j0 + 1) * 512 + l * 8;

#define GSTAGE(ASB, BSB, kt)            \
    gload16(Ag0 + (kt), (ASB) + lo0);   \
    gload16(Ag1 + (kt), (ASB) + lo1);   \
    gload16(Bg0 + (kt), (BSB) + lo0);   \
    gload16(Bg1 + (kt), (BSB) + lo1)

    f32x4 acc[4][4] = {};
    GSTAGE(As0, Bs0, 0);
    WAIT_BAR();
    for (int kt = 0; kt < 1024; kt += 64) {
        if (kt + 32 < 1024) { GSTAGE(As1, Bs1, kt + 32); }
        gemm_step(As0, Bs0, wm, wn, fr, f8, acc);
        WAIT_BAR();
        if (kt + 64 < 1024) { GSTAGE(As0, Bs0, kt + 64); }
        gemm_step(As1, Bs1, wm, wn, fr, f8, acc);
        WAIT_BAR();
    }
#undef GSTAGE
    // epilogue: C/D layout col=lane&15, row=(lane>>4)*4+r  [HW-verified]
#pragma unroll
    for (int mt = 0; mt < 4; ++mt) {
        float rb_[4];
#pragma unroll
        for (int r = 0; r < 4; ++r)
            rb_[r] = bias_row ? bias[m0 + wm + mt * 16 + f4 + r] * bias_scale : 0.f;
#pragma unroll
        for (int nt = 0; nt < 4; ++nt) {
            const size_t col = n0 + wn + nt * 16 + fr;
            const float cb = bias_row ? 0.f : bias[col] * bias_scale;
#pragma unroll
            for (int r = 0; r < 4; ++r) {
                const size_t row = m0 + wm + mt * 16 + f4 + r;
                const float vv = acc[mt][nt][r] + cb + rb_[r];
                if (of32) of32[row * (size_t)ldc + col] = vv;
                else      obf[row * (size_t)ldc + col] = f2bf(vv);
            }
        }
    }
}

// ---------------- flash attention ----------------
static __device__ __forceinline__ void softmax_grp(const f32x4 s[4], f32x4 o[4],
                                                   float& m, float& lsum, bf16x4 p[4]) {
    float tmax = s[0][0];
#pragma unroll
    for (int nt = 0; nt < 4; ++nt)
#pragma unroll
        for (int r = 0; r < 4; ++r) tmax = fmaxf(tmax, s[nt][r]);
    tmax = fmaxf(tmax, __shfl_xor(tmax, 16, 64));
    tmax = fmaxf(tmax, __shfl_xor(tmax, 32, 64));
    float ps = 0.f;
    if (__any(tmax > 11.0f)) {            // T13 defer-rescale: rare with this data
        const float d = fmaxf(tmax, 0.f);
        const float fac = exp2f_fast(-d);
        m += d; lsum *= fac;
#pragma unroll
        for (int mt = 0; mt < 4; ++mt)
#pragma unroll
            for (int r = 0; r < 4; ++r) o[mt][r] *= fac;
#pragma unroll
        for (int nt = 0; nt < 4; ++nt)
#pragma unroll
            for (int r = 0; r < 4; ++r) {
                const float pp = exp2f_fast(s[nt][r] - d);
                ps += pp; p[nt][r] = (__bf16)pp;
            }
    } else {
#pragma unroll
        for (int nt = 0; nt < 4; ++nt)
#pragma unroll
            for (int r = 0; r < 4; ++r) {
                const float pp = exp2f_fast(s[nt][r]);
                ps += pp; p[nt][r] = (__bf16)pp;
            }
    }
    ps += __shfl_xor(ps, 16, 64);
    ps += __shfl_xor(ps, 32, 64);
    lsum += ps;
}

static __device__ __forceinline__ void flash_tile(const u16* Ks, const u16* Vs,
                                                  int fr, int gg,
                                                  bf16x8 qA0, bf16x8 qA1, bf16x8 qB0, bf16x8 qB1,
                                                  f32x4 oA[4], f32x4 oB[4],
                                                  float& mA, float& lA, float& mB, float& lB) {
    // S^T = mfma(K, Q) with C-init = -m (log2 domain); lane q = fr, k = nt*16+gg*4+r
    f32x4 sA[4], sB[4];
    __builtin_amdgcn_s_setprio(1);
#pragma unroll
    for (int nt = 0; nt < 4; ++nt) {
        const int rk = nt * 16 + fr;
        const bf16x8 kf0 = *(const bf16x8*)(&Ks[SWZ64(rk, gg)]);
        const bf16x8 kf1 = *(const bf16x8*)(&Ks[SWZ64(rk, gg + 4)]);
        f32x4 z = {-mA, -mA, -mA, -mA};
        z = __builtin_amdgcn_mfma_f32_16x16x32_bf16(kf0, qA0, z, 0, 0, 0);
        z = __builtin_amdgcn_mfma_f32_16x16x32_bf16(kf1, qA1, z, 0, 0, 0);
        sA[nt] = z;
        f32x4 y = {-mB, -mB, -mB, -mB};
        y = __builtin_amdgcn_mfma_f32_16x16x32_bf16(kf0, qB0, y, 0, 0, 0);
        y = __builtin_amdgcn_mfma_f32_16x16x32_bf16(kf1, qB1, y, 0, 0, 0);
        sB[nt] = y;
    }
    __builtin_amdgcn_s_setprio(0);
    bf16x4 pA[4], pB[4];
    softmax_grp(sA, oA, mA, lA, pA);
    softmax_grp(sB, oB, mB, lB, pB);
    // B-fragments straight from registers (k-permutation invariance)
    const bf16x8 BA0 = __builtin_shufflevector(pA[0], pA[1], 0, 1, 2, 3, 4, 5, 6, 7);
    const bf16x8 BA1 = __builtin_shufflevector(pA[2], pA[3], 0, 1, 2, 3, 4, 5, 6, 7);
    const bf16x8 BB0 = __builtin_shufflevector(pB[0], pB[1], 0, 1, 2, 3, 4, 5, 6, 7);
    const bf16x8 BB1 = __builtin_shufflevector(pB[2], pB[3], 0, 1, 2, 3, 4, 5, 6, 7);
    // PV: A-frag reg j = V^T[hd][(j>>2)*16 + gg*4 + (j&3)] (matching permuted k-order)
    const int e0 = gg >> 1, hf = (gg & 1) * 4;
    __builtin_amdgcn_s_setprio(1);
#pragma unroll
    for (int mt = 0; mt < 4; ++mt) {
        const int rv = mt * 16 + fr;
        const int rs = rv & 7, rb = rv * 64;
        const bf16x4 v0 = *(const bf16x4*)(&Vs[rb + (((e0    ) ^ rs) << 3) + hf]);
        const bf16x4 v1 = *(const bf16x4*)(&Vs[rb + (((e0 + 2) ^ rs) << 3) + hf]);
        const bf16x4 v2 = *(const bf16x4*)(&Vs[rb + (((e0 + 4) ^ rs) << 3) + hf]);
        const bf16x4 v3 = *(const bf16x4*)(&Vs[rb + (((e0 + 6) ^ rs) << 3) + hf]);
        const bf16x8 vk0 = __builtin_shufflevector(v0, v1, 0, 1, 2, 3, 4, 5, 6, 7);
        const bf16x8 vk1 = __builtin_shufflevector(v2, v3, 0, 1, 2, 3, 4, 5, 6, 7);
        oA[mt] = __builtin_amdgcn_mfma_f32_16x16x32_bf16(vk0, BA0, oA[mt], 0, 0, 0);
        oA[mt] = __builtin_amdgcn_mfma_f32_16x16x32_bf16(vk1, BA1, oA[mt], 0, 0, 0);
        oB[mt] = __builtin_amdgcn_mfma_f32_16x16x32_bf16(vk0, BB0, oB[mt], 0, 0, 0);
        oB[mt] = __builtin_amdgcn_mfma_f32_16x16x32_bf16(vk1, BB1, oB[mt], 0, 0, 0);
    }
    __builtin_amdgcn_s_setprio(0);
}

// 1D grid 1024 blocks (XCD-bijective swizzle -> K/V L2-resident). 4 waves, 32 q-rows/wave
// (groups A/B). V read directly from Vt2[n_global][t_global] (ld=8192) - no vtrans kernel.
// 2-phase double-buffered K/V staging, fused vmcnt(0)+s_barrier per tile.
// launch_bounds min-waves=2: cap VGPR at 256 so the dbuf structure does NOT spill
// (round 4's (256,4) forced allocator under the doubled live ranges -> 132 MB scratch writes).
__global__ __launch_bounds__(256, 2) void k_flash(const u16* __restrict__ Q, const u16* __restrict__ K,
                                                  const u16* __restrict__ Vt2, u16* __restrict__ O) {
    __shared__ u16 Ks0[64 * 64], Vs0[64 * 64];
    __shared__ u16 Ks1[64 * 64], Vs1[64 * 64];
    const int tid = threadIdx.x;
    const int l = tid & 63, w = tid >> 6;
    const int id = blockIdx.x;
    const int swz = (id & 7) * 128 + (id >> 3);      // bijective XCD swizzle (1024 % 8 == 0)
    const int bh = swz >> 3, qt = swz & 7;
    const int b = bh >> 4, h = bh & 15;
    const int qw = qt * 128 + w * 32;
    const int fr = l & 15, gg = l >> 4, f4 = gg * 4, f8 = gg * 8;

    // Q fragments (SCALE*LOG2E folded into Wq/bq)
    const u16* qpA = Q + ((size_t)(b * 1024 + qw + fr)) * 1024 + h * 64 + f8;
    const u16* qpB = qpA + 16 * 1024;
    const bf16x8 qA0 = *(const bf16x8*)qpA;
    const bf16x8 qA1 = *(const bf16x8*)(qpA + 32);
    const bf16x8 qB0 = *(const bf16x8*)qpB;
    const bf16x8 qB1 = *(const bf16x8*)(qpB + 32);

    // staging: chunk j (0..7) = rows j*8..j*8+7; lane l -> row j*8+(l>>3),
    // source 16B-chunk (l&7)^(l>>3) (pre-swizzled source, linear LDS dest)
    const int jj0 = w * 2, jj1 = w * 2 + 1;
    const int sr0 = jj0 * 8 + (l >> 3), sr1 = jj1 * 8 + (l >> 3);
    const int sc = ((l & 7) ^ (l >> 3)) * 8;
    const u16* kg0 = K + ((size_t)(b * 1024 + sr0)) * 1024 + h * 64 + sc;
    const u16* kg1 = K + ((size_t)(b * 1024 + sr1)) * 1024 + h * 64 + sc;
    const u16* vg0 = Vt2 + ((size_t)(h * 64 + sr0)) * 8192 + b * 1024 + sc;
    const u16* vg1 = Vt2 + ((size_t)(h * 64 + sr1)) * 8192 + b * 1024 + sc;
    const int lk0 = jj0 * 512 + l * 8, lk1 = jj1 * 512 + l * 8;

#define FSTAGE(KSB, VSB, kt)                            \
    gload16(kg0 + (size_t)(kt) * 1024, (KSB) + lk0);    \
    gload16(kg1 + (size_t)(kt) * 1024, (KSB) + lk1);    \
    gload16(vg0 + (kt), (VSB) + lk0);                   \
    gload16(vg1 + (kt), (VSB) + lk1)

    f32x4 oA[4] = {}, oB[4] = {};
    float mA = 0.f, lA = 0.f, mB = 0.f, lB = 0.f;

    FSTAGE(Ks0, Vs0, 0);
    WAIT_BAR();
    for (int kt0 = 0; kt0 < 1024; kt0 += 128) {
        if (kt0 + 64 < 1024) { FSTAGE(Ks1, Vs1, kt0 + 64); }
        flash_tile(Ks0, Vs0, fr, gg, qA0, qA1, qB0, qB1, oA, oB, mA, lA, mB, lB);
        WAIT_BAR();
        if (kt0 + 128 < 1024) { FSTAGE(Ks0, Vs0, kt0 + 128); }
        flash_tile(Ks1, Vs1, fr, gg, qA0, qA1, qB0, qB1, oA, oB, mA, lA, mB, lB);
        WAIT_BAR();
    }
#undef FSTAGE
    // epilogue: O[t][h*64 + mt*16 + f4 + r]
    const float ivA = 1.0f / lA, ivB = 1.0f / lB;
    u16* opA = O + ((size_t)(b * 1024 + qw + fr)) * 1024 + h * 64;
    u16* opB = opA + 16 * 1024;
#pragma unroll
    for (int mt = 0; mt < 4; ++mt) {
        u16x4 oa, ob;
#pragma unroll
        for (int r = 0; r < 4; ++r) { oa[r] = f2bf(oA[mt][r] * ivA); ob[r] = f2bf(oB[mt][r] * ivB); }
        *(u16x4*)(opA + mt * 16 + f4) = oa;
        *(u16x4*)(opB + mt * 16 + f4) = ob;
    }
}

extern "C" void kernel_launch(void* const* d_in, const int* in_sizes, int n_in,
                              void* d_out, int out_size, void* d_ws, size_t ws_size,
                              hipStream_t stream) {
    (void)in_sizes; (void)n_in; (void)out_size; (void)ws_size;
    const float* hs = (const float*)d_in[0];
    const float* Wq = (const float*)d_in[1];
    const float* bq = (const float*)d_in[2];
    const float* Wk = (const float*)d_in[3];
    const float* bk = (const float*)d_in[4];
    const float* Wv = (const float*)d_in[5];
    const float* bv = (const float*)d_in[6];
    const float* Wo = (const float*)d_in[7];
    const float* bo = (const float*)d_in[8];
    float* out = (float*)d_out;
    char* ws = (char*)d_ws;
    const size_t MB = 1024ull * 1024ull;
    u16* Xb  = (u16*)(ws);            // 16 MB (dead after last GEMM use; reused as attn output Ob)
    u16* Wqt = (u16*)(ws + 16 * MB);  // 2 MB each
    u16* Wkt = (u16*)(ws + 18 * MB);
    u16* Wvt = (u16*)(ws + 20 * MB);
    u16* Wot = (u16*)(ws + 22 * MB);
    u16* Qb  = (u16*)(ws + 24 * MB);  // 16 MB
    u16* Kb  = (u16*)(ws + 40 * MB);  // 16 MB
    u16* Vt2 = (u16*)(ws + 56 * MB);  // 16 MB: V^T[n_global][t_global], ld=8192 -> 72 MB total
    u16* Ob  = Xb;

    // HD^-0.5 * log2(e) folded into Wq and bq (softmax runs in log2 domain)
    const float SCALE_Q = 0.125f * 1.4426950408889634f;

    k_cvt<<<dim3(8192), dim3(256), 0, stream>>>(hs, Xb);
    k_wtrans4<<<dim3(32, 32, 4), dim3(256), 0, stream>>>(Wq, Wk, Wv, Wo, Wqt, Wkt, Wvt, Wot, SCALE_Q);
    k_gemm<<<dim3(8, 64), dim3(256), 0, stream>>>(Xb, Wqt, bq, SCALE_Q, Qb, nullptr, 1024, 0);
    k_gemm<<<dim3(8, 64), dim3(256), 0, stream>>>(Xb, Wkt, bk, 1.0f, Kb, nullptr, 1024, 0);
    // V^T = Wv^T * X^T : A = Wvt [n][k], Bt = Xb [t][k], C = Vt2 [n][t] (ld 8192), bias per row
    k_gemm<<<dim3(64, 8), dim3(256), 0, stream>>>(Wvt, Xb, bv, 1.0f, Vt2, nullptr, 8192, 1);
    k_flash<<<dim3(1024), dim3(256), 0, stream>>>(Qb, Kb, Vt2, Ob);
    k_gemm<<<dim3(8, 64), dim3(256), 0, stream>>>(Ob, Wot, bo, 1.0f, nullptr, out, 1024, 0);
}

// Round 6
// 180.423 us; speedup vs baseline: 1.2396x; 1.1328x over previous
//
#include <hip/hip_runtime.h>

typedef unsigned short u16;
typedef __attribute__((ext_vector_type(4))) float f32x4;
typedef __attribute__((ext_vector_type(8))) __bf16 bf16x8;
typedef __attribute__((ext_vector_type(4))) __bf16 bf16x4;
typedef __attribute__((ext_vector_type(4))) unsigned short u16x4;
typedef __attribute__((ext_vector_type(8))) unsigned short u16x8;

// round-to-nearest-even fp32 -> bf16 (used in epilogues / converts)
static __device__ __forceinline__ u16 f2bf(float f) {
    union { float f; unsigned u; } v; v.f = f;
    unsigned r = v.u + 0x7FFFu + ((v.u >> 16) & 1u);
    return (u16)(r >> 16);
}

// v_exp_f32: D = 2^x
static __device__ __forceinline__ float exp2f_fast(float x) {
    float r; asm("v_exp_f32 %0, %1" : "=v"(r) : "v"(x)); return r;
}

// async global->LDS, 16 bytes per lane (dest must be uniform base + lane*16)
static __device__ __forceinline__ void gload16(const u16* g, u16* l) {
    __builtin_amdgcn_global_load_lds(
        (const __attribute__((address_space(1))) unsigned int*)g,
        (__attribute__((address_space(3))) unsigned int*)l, 16, 0, 0);
}

// fused counted-wait + raw barrier
#define WAIT_BAR() asm volatile("s_waitcnt vmcnt(0)\n\ts_barrier" ::: "memory")

// swizzled element offset in a [rows][64] u16 tile (128B rows, XOR 16B-chunk by row&7)
#define SWZ64(row, ec) (((row) * 64) + ((((ec) ^ ((row) & 7))) << 3))

// ---------------- fp32 -> bf16 convert (4 elems/thread) ----------------
__global__ __launch_bounds__(256) void k_cvt(const float* __restrict__ in, u16* __restrict__ out) {
    size_t i = (size_t)blockIdx.x * 256 + threadIdx.x;
    float4 v = ((const float4*)in)[i];
    u16x4 o; o[0] = f2bf(v.x); o[1] = f2bf(v.y); o[2] = f2bf(v.z); o[3] = f2bf(v.w);
    *(u16x4*)(out + i * 4) = o;
}

// ---------------- 4x W [K=1024][N=1024] fp32 -> Wt [N][K] bf16 (scaled), one launch ----------------
__global__ __launch_bounds__(256) void k_wtrans4(
    const float* __restrict__ W0, const float* __restrict__ W1,
    const float* __restrict__ W2, const float* __restrict__ W3,
    u16* __restrict__ T0, u16* __restrict__ T1, u16* __restrict__ T2, u16* __restrict__ T3,
    float s0) {
    const float* W; u16* Tt; float sc;
    switch (blockIdx.z) {
        case 0:  W = W0; Tt = T0; sc = s0;  break;
        case 1:  W = W1; Tt = T1; sc = 1.f; break;
        case 2:  W = W2; Tt = T2; sc = 1.f; break;
        default: W = W3; Tt = T3; sc = 1.f; break;
    }
    __shared__ float tile[32][33];
    int n0 = blockIdx.x * 32, k0 = blockIdx.y * 32;
    int tid = threadIdx.x;
    int r = tid >> 3, c = (tid & 7) * 4;
    float4 v = *(const float4*)(W + (size_t)(k0 + r) * 1024 + n0 + c);
    tile[r][c] = v.x; tile[r][c + 1] = v.y; tile[r][c + 2] = v.z; tile[r][c + 3] = v.w;
    __syncthreads();
    u16x4 o;
    o[0] = f2bf(tile[c][r] * sc);
    o[1] = f2bf(tile[c + 1][r] * sc);
    o[2] = f2bf(tile[c + 2][r] * sc);
    o[3] = f2bf(tile[c + 3][r] * sc);
    *(u16x4*)(Tt + (size_t)(n0 + r) * 1024 + k0 + c) = o;
}

// ---------------- shared GEMM main-loop pieces (128x128 tile, BK=32, dbuf) ----------------
static __device__ __forceinline__ void gemm_step(const u16* As, const u16* Bs,
                                                 int wm, int wn, int fr, int f8,
                                                 f32x4 acc[4][4]) {
    bf16x8 af[4], bf[4];
#pragma unroll
    for (int mt = 0; mt < 4; ++mt) af[mt] = *(const bf16x8*)(&As[(wm + mt * 16 + fr) * 32 + f8]);
#pragma unroll
    for (int nt = 0; nt < 4; ++nt) bf[nt] = *(const bf16x8*)(&Bs[(wn + nt * 16 + fr) * 32 + f8]);
#pragma unroll
    for (int mt = 0; mt < 4; ++mt)
#pragma unroll
        for (int nt = 0; nt < 4; ++nt)
            acc[mt][nt] = __builtin_amdgcn_mfma_f32_16x16x32_bf16(af[mt], bf[nt], acc[mt][nt], 0, 0, 0);
}

#define GEMM_PRELUDE(A_, B_)                                                    \
    const int tid = threadIdx.x;                                                \
    const int l = tid & 63, w = tid >> 6;                                       \
    const int wm = (w >> 1) * 64, wn = (w & 1) * 64;                            \
    const size_t m0 = (size_t)blockIdx.y * 128, n0 = (size_t)blockIdx.x * 128;  \
    const int fr = l & 15, f8 = (l >> 4) * 8, f4 = (l >> 4) * 4;                \
    const int j0 = w * 2;                                                       \
    const int srow0 = j0 * 16 + (l >> 2), srow1 = srow0 + 16;                   \
    const int scol = (l & 3) * 8;                                               \
    const u16* Ag0 = (A_) + (m0 + srow0) * 1024 + scol;                         \
    const u16* Ag1 = (A_) + (m0 + srow1) * 1024 + scol;                         \
    const u16* Bg0 = (B_) + (n0 + srow0) * 1024 + scol;                         \
    const u16* Bg1 = (B_) + (n0 + srow1) * 1024 + scol;                         \
    const int lo0 = j0 * 512 + l * 8, lo1 = (j0 + 1) * 512 + l * 8;

#define GSTAGE(ASB, BSB, kt)            \
    gload16(Ag0 + (kt), (ASB) + lo0);   \
    gload16(Ag1 + (kt), (ASB) + lo1);   \
    gload16(Bg0 + (kt), (BSB) + lo0);   \
    gload16(Bg1 + (kt), (BSB) + lo1)

#define GEMM_MAINLOOP()                                           \
    f32x4 acc[4][4] = {};                                         \
    GSTAGE(As0, Bs0, 0);                                          \
    WAIT_BAR();                                                   \
    for (int kt = 0; kt < 1024; kt += 64) {                       \
        if (kt + 32 < 1024) { GSTAGE(As1, Bs1, kt + 32); }        \
        gemm_step(As0, Bs0, wm, wn, fr, f8, acc);                 \
        WAIT_BAR();                                               \
        if (kt + 64 < 1024) { GSTAGE(As0, Bs0, kt + 64); }        \
        gemm_step(As1, Bs1, wm, wn, fr, f8, acc);                 \
        WAIT_BAR();                                               \
    }

// ---------------- generic GEMM (used for V^T and output projection) ----------------
__global__ __launch_bounds__(256) void k_gemm(const u16* __restrict__ A, const u16* __restrict__ Bt,
                                              const float* __restrict__ bias, float bias_scale,
                                              u16* __restrict__ obf, float* __restrict__ of32,
                                              int ldc, int bias_row) {
    __shared__ u16 As0[128 * 32], Bs0[128 * 32];
    __shared__ u16 As1[128 * 32], Bs1[128 * 32];
    GEMM_PRELUDE(A, Bt)
    GEMM_MAINLOOP()
    // epilogue: C/D layout col=lane&15, row=(lane>>4)*4+r  [HW-verified]
#pragma unroll
    for (int mt = 0; mt < 4; ++mt) {
        float rb_[4];
#pragma unroll
        for (int r = 0; r < 4; ++r)
            rb_[r] = bias_row ? bias[m0 + wm + mt * 16 + f4 + r] * bias_scale : 0.f;
#pragma unroll
        for (int nt = 0; nt < 4; ++nt) {
            const size_t col = n0 + wn + nt * 16 + fr;
            const float cb = bias_row ? 0.f : bias[col] * bias_scale;
#pragma unroll
            for (int r = 0; r < 4; ++r) {
                const size_t row = m0 + wm + mt * 16 + f4 + r;
                const float vv = acc[mt][nt][r] + cb + rb_[r];
                if (of32) of32[row * (size_t)ldc + col] = vv;
                else      obf[row * (size_t)ldc + col] = f2bf(vv);
            }
        }
    }
}

// ---------------- fused Q+K projection: Bt = stacked [Wqt;Wkt] (N=2048), grid (16,64) ----------------
// 1024 blocks = 4 blocks/CU -> double the cross-block overlap of the 512-block variant.
__global__ __launch_bounds__(256) void k_gemmQK(const u16* __restrict__ A, const u16* __restrict__ Wqkt,
                                                const float* __restrict__ bq, const float* __restrict__ bk,
                                                float qscale, u16* __restrict__ Qb, u16* __restrict__ Kb) {
    __shared__ u16 As0[128 * 32], Bs0[128 * 32];
    __shared__ u16 As1[128 * 32], Bs1[128 * 32];
    GEMM_PRELUDE(A, Wqkt)
    GEMM_MAINLOOP()
    const int seg = (int)(n0 >> 10);                 // block-uniform: 0 -> Q, 1 -> K
    const float* bias = seg ? bk : bq;
    const float bsc = seg ? 1.f : qscale;
    u16* ob = seg ? Kb : Qb;
#pragma unroll
    for (int mt = 0; mt < 4; ++mt)
#pragma unroll
        for (int nt = 0; nt < 4; ++nt) {
            const size_t colm = (n0 + wn + nt * 16 + fr) & 1023;
            const float bb = bias[colm] * bsc;
#pragma unroll
            for (int r = 0; r < 4; ++r) {
                const size_t row = m0 + wm + mt * 16 + f4 + r;
                ob[row * 1024 + colm] = f2bf(acc[mt][nt][r] + bb);
            }
        }
}

// ---------------- flash attention ----------------
// Softmax with NO cross-lane ops in the common path: defer-rescale check is a vote on the
// per-lane 16-element max; lsum is a per-lane partial reduced once at the epilogue. The rare
// exact path (any s > 11, never hit with this data) does the shuffled row-max + rescale;
// fac is group-uniform so scaling each lane's partial lsum stays exact.
static __device__ __forceinline__ void softmax_grp(const f32x4 s[4], f32x4 o[4],
                                                   float& m, float& lsum, bf16x4 p[4]) {
    float mymax = s[0][0];
#pragma unroll
    for (int nt = 0; nt < 4; ++nt)
#pragma unroll
        for (int r = 0; r < 4; ++r) mymax = fmaxf(mymax, s[nt][r]);
    float ps = 0.f;
#pragma unroll
    for (int nt = 0; nt < 4; ++nt)
#pragma unroll
        for (int r = 0; r < 4; ++r) {
            const float pp = exp2f_fast(s[nt][r]);
            ps += pp; p[nt][r] = (__bf16)pp;
        }
    if (__builtin_expect(__any(mymax > 11.0f), 0)) {   // wave-uniform rare path
        float rm = fmaxf(mymax, __shfl_xor(mymax, 16, 64));
        rm = fmaxf(rm, __shfl_xor(rm, 32, 64));
        const float d = fmaxf(rm, 0.f);
        const float fac = exp2f_fast(-d);
        m += d; lsum *= fac;
#pragma unroll
        for (int mt = 0; mt < 4; ++mt)
#pragma unroll
            for (int r = 0; r < 4; ++r) o[mt][r] *= fac;
        ps = 0.f;
#pragma unroll
        for (int nt = 0; nt < 4; ++nt)
#pragma unroll
            for (int r = 0; r < 4; ++r) {
                const float pp = exp2f_fast(s[nt][r] - d);
                ps += pp; p[nt][r] = (__bf16)pp;
            }
    }
    lsum += ps;
}

static __device__ __forceinline__ void flash_tile(const u16* Ks, const u16* Vs,
                                                  int fr, int gg,
                                                  bf16x8 qA0, bf16x8 qA1, bf16x8 qB0, bf16x8 qB1,
                                                  f32x4 oA[4], f32x4 oB[4],
                                                  float& mA, float& lA, float& mB, float& lB) {
    // S^T = mfma(K, Q) with C-init = -m (log2 domain); lane q = fr, k = nt*16+gg*4+r
    f32x4 sA[4], sB[4];
    __builtin_amdgcn_s_setprio(1);
#pragma unroll
    for (int nt = 0; nt < 4; ++nt) {
        const int rk = nt * 16 + fr;
        const bf16x8 kf0 = *(const bf16x8*)(&Ks[SWZ64(rk, gg)]);
        const bf16x8 kf1 = *(const bf16x8*)(&Ks[SWZ64(rk, gg + 4)]);
        f32x4 z = {-mA, -mA, -mA, -mA};
        z = __builtin_amdgcn_mfma_f32_16x16x32_bf16(kf0, qA0, z, 0, 0, 0);
        z = __builtin_amdgcn_mfma_f32_16x16x32_bf16(kf1, qA1, z, 0, 0, 0);
        sA[nt] = z;
        f32x4 y = {-mB, -mB, -mB, -mB};
        y = __builtin_amdgcn_mfma_f32_16x16x32_bf16(kf0, qB0, y, 0, 0, 0);
        y = __builtin_amdgcn_mfma_f32_16x16x32_bf16(kf1, qB1, y, 0, 0, 0);
        sB[nt] = y;
    }
    __builtin_amdgcn_s_setprio(0);
    bf16x4 pA[4], pB[4];
    softmax_grp(sA, oA, mA, lA, pA);
    softmax_grp(sB, oB, mB, lB, pB);
    // B-fragments straight from registers (k-permutation invariance)
    const bf16x8 BA0 = __builtin_shufflevector(pA[0], pA[1], 0, 1, 2, 3, 4, 5, 6, 7);
    const bf16x8 BA1 = __builtin_shufflevector(pA[2], pA[3], 0, 1, 2, 3, 4, 5, 6, 7);
    const bf16x8 BB0 = __builtin_shufflevector(pB[0], pB[1], 0, 1, 2, 3, 4, 5, 6, 7);
    const bf16x8 BB1 = __builtin_shufflevector(pB[2], pB[3], 0, 1, 2, 3, 4, 5, 6, 7);
    // PV: A-frag reg j = V^T[hd][(j>>2)*16 + gg*4 + (j&3)] (matching permuted k-order)
    const int e0 = gg >> 1, hf = (gg & 1) * 4;
    __builtin_amdgcn_s_setprio(1);
#pragma unroll
    for (int mt = 0; mt < 4; ++mt) {
        const int rv = mt * 16 + fr;
        const int rs = rv & 7, rb = rv * 64;
        const bf16x4 v0 = *(const bf16x4*)(&Vs[rb + (((e0    ) ^ rs) << 3) + hf]);
        const bf16x4 v1 = *(const bf16x4*)(&Vs[rb + (((e0 + 2) ^ rs) << 3) + hf]);
        const bf16x4 v2 = *(const bf16x4*)(&Vs[rb + (((e0 + 4) ^ rs) << 3) + hf]);
        const bf16x4 v3 = *(const bf16x4*)(&Vs[rb + (((e0 + 6) ^ rs) << 3) + hf]);
        const bf16x8 vk0 = __builtin_shufflevector(v0, v1, 0, 1, 2, 3, 4, 5, 6, 7);
        const bf16x8 vk1 = __builtin_shufflevector(v2, v3, 0, 1, 2, 3, 4, 5, 6, 7);
        oA[mt] = __builtin_amdgcn_mfma_f32_16x16x32_bf16(vk0, BA0, oA[mt], 0, 0, 0);
        oA[mt] = __builtin_amdgcn_mfma_f32_16x16x32_bf16(vk1, BA1, oA[mt], 0, 0, 0);
        oB[mt] = __builtin_amdgcn_mfma_f32_16x16x32_bf16(vk0, BB0, oB[mt], 0, 0, 0);
        oB[mt] = __builtin_amdgcn_mfma_f32_16x16x32_bf16(vk1, BB1, oB[mt], 0, 0, 0);
    }
    __builtin_amdgcn_s_setprio(0);
}

// 1D grid 1024 blocks (XCD-bijective swizzle -> K/V L2-resident). 4 waves, 32 q-rows/wave
// (groups A/B). V read directly from Vt2[n_global][t_global] (ld=8192).
// 2-phase double-buffered K/V staging, fused vmcnt(0)+s_barrier per tile.
__global__ __launch_bounds__(256, 2) void k_flash(const u16* __restrict__ Q, const u16* __restrict__ K,
                                                  const u16* __restrict__ Vt2, u16* __restrict__ O) {
    __shared__ u16 Ks0[64 * 64], Vs0[64 * 64];
    __shared__ u16 Ks1[64 * 64], Vs1[64 * 64];
    const int tid = threadIdx.x;
    const int l = tid & 63, w = tid >> 6;
    const int id = blockIdx.x;
    const int swz = (id & 7) * 128 + (id >> 3);      // bijective XCD swizzle (1024 % 8 == 0)
    const int bh = swz >> 3, qt = swz & 7;
    const int b = bh >> 4, h = bh & 15;
    const int qw = qt * 128 + w * 32;
    const int fr = l & 15, gg = l >> 4, f4 = gg * 4, f8 = gg * 8;

    // Q fragments (SCALE*LOG2E folded into Wq/bq)
    const u16* qpA = Q + ((size_t)(b * 1024 + qw + fr)) * 1024 + h * 64 + f8;
    const u16* qpB = qpA + 16 * 1024;
    const bf16x8 qA0 = *(const bf16x8*)qpA;
    const bf16x8 qA1 = *(const bf16x8*)(qpA + 32);
    const bf16x8 qB0 = *(const bf16x8*)qpB;
    const bf16x8 qB1 = *(const bf16x8*)(qpB + 32);

    // staging: chunk j (0..7) = rows j*8..j*8+7; lane l -> row j*8+(l>>3),
    // source 16B-chunk (l&7)^(l>>3) (pre-swizzled source, linear LDS dest)
    const int jj0 = w * 2, jj1 = w * 2 + 1;
    const int sr0 = jj0 * 8 + (l >> 3), sr1 = jj1 * 8 + (l >> 3);
    const int sc = ((l & 7) ^ (l >> 3)) * 8;
    const u16* kg0 = K + ((size_t)(b * 1024 + sr0)) * 1024 + h * 64 + sc;
    const u16* kg1 = K + ((size_t)(b * 1024 + sr1)) * 1024 + h * 64 + sc;
    const u16* vg0 = Vt2 + ((size_t)(h * 64 + sr0)) * 8192 + b * 1024 + sc;
    const u16* vg1 = Vt2 + ((size_t)(h * 64 + sr1)) * 8192 + b * 1024 + sc;
    const int lk0 = jj0 * 512 + l * 8, lk1 = jj1 * 512 + l * 8;

#define FSTAGE(KSB, VSB, kt)                            \
    gload16(kg0 + (size_t)(kt) * 1024, (KSB) + lk0);    \
    gload16(kg1 + (size_t)(kt) * 1024, (KSB) + lk1);    \
    gload16(vg0 + (kt), (VSB) + lk0);                   \
    gload16(vg1 + (kt), (VSB) + lk1)

    f32x4 oA[4] = {}, oB[4] = {};
    float mA = 0.f, lA = 0.f, mB = 0.f, lB = 0.f;   // lA/lB are per-lane partials

    FSTAGE(Ks0, Vs0, 0);
    WAIT_BAR();
    for (int kt0 = 0; kt0 < 1024; kt0 += 128) {
        if (kt0 + 64 < 1024) { FSTAGE(Ks1, Vs1, kt0 + 64); }
        flash_tile(Ks0, Vs0, fr, gg, qA0, qA1, qB0, qB1, oA, oB, mA, lA, mB, lB);
        WAIT_BAR();
        if (kt0 + 128 < 1024) { FSTAGE(Ks0, Vs0, kt0 + 128); }
        flash_tile(Ks1, Vs1, fr, gg, qA0, qA1, qB0, qB1, oA, oB, mA, lA, mB, lB);
        WAIT_BAR();
    }
#undef FSTAGE
    // epilogue: cross-lane lsum reduce (once), then O[t][h*64 + mt*16 + f4 + r]
    lA += __shfl_xor(lA, 16, 64); lA += __shfl_xor(lA, 32, 64);
    lB += __shfl_xor(lB, 16, 64); lB += __shfl_xor(lB, 32, 64);
    const float ivA = 1.0f / lA, ivB = 1.0f / lB;
    u16* opA = O + ((size_t)(b * 1024 + qw + fr)) * 1024 + h * 64;
    u16* opB = opA + 16 * 1024;
#pragma unroll
    for (int mt = 0; mt < 4; ++mt) {
        u16x4 oa, ob;
#pragma unroll
        for (int r = 0; r < 4; ++r) { oa[r] = f2bf(oA[mt][r] * ivA); ob[r] = f2bf(oB[mt][r] * ivB); }
        *(u16x4*)(opA + mt * 16 + f4) = oa;
        *(u16x4*)(opB + mt * 16 + f4) = ob;
    }
}

extern "C" void kernel_launch(void* const* d_in, const int* in_sizes, int n_in,
                              void* d_out, int out_size, void* d_ws, size_t ws_size,
                              hipStream_t stream) {
    (void)in_sizes; (void)n_in; (void)out_size; (void)ws_size;
    const float* hs = (const float*)d_in[0];
    const float* Wq = (const float*)d_in[1];
    const float* bq = (const float*)d_in[2];
    const float* Wk = (const float*)d_in[3];
    const float* bk = (const float*)d_in[4];
    const float* Wv = (const float*)d_in[5];
    const float* bv = (const float*)d_in[6];
    const float* Wo = (const float*)d_in[7];
    const float* bo = (const float*)d_in[8];
    float* out = (float*)d_out;
    char* ws = (char*)d_ws;
    const size_t MB = 1024ull * 1024ull;
    u16* Xb  = (u16*)(ws);            // 16 MB (dead after last GEMM use; reused as attn output Ob)
    u16* Wqt = (u16*)(ws + 16 * MB);  // 2 MB each; Wqt+Wkt adjacent => stacked [2048][1024] for k_gemmQK
    u16* Wkt = (u16*)(ws + 18 * MB);
    u16* Wvt = (u16*)(ws + 20 * MB);
    u16* Wot = (u16*)(ws + 22 * MB);
    u16* Qb  = (u16*)(ws + 24 * MB);  // 16 MB
    u16* Kb  = (u16*)(ws + 40 * MB);  // 16 MB
    u16* Vt2 = (u16*)(ws + 56 * MB);  // 16 MB: V^T[n_global][t_global], ld=8192 -> 72 MB total
    u16* Ob  = Xb;

    // HD^-0.5 * log2(e) folded into Wq and bq (softmax runs in log2 domain)
    const float SCALE_Q = 0.125f * 1.4426950408889634f;

    k_cvt<<<dim3(8192), dim3(256), 0, stream>>>(hs, Xb);
    k_wtrans4<<<dim3(32, 32, 4), dim3(256), 0, stream>>>(Wq, Wk, Wv, Wo, Wqt, Wkt, Wvt, Wot, SCALE_Q);
    // fused Q+K projection: N=2048 over stacked [Wqt;Wkt], 1024 blocks (4/CU)
    k_gemmQK<<<dim3(16, 64), dim3(256), 0, stream>>>(Xb, Wqt, bq, bk, SCALE_Q, Qb, Kb);
    // V^T = Wv^T * X^T : A = Wvt [n][k], Bt = Xb [t][k], C = Vt2 [n][t] (ld 8192), bias per row
    k_gemm<<<dim3(64, 8), dim3(256), 0, stream>>>(Wvt, Xb, bv, 1.0f, Vt2, nullptr, 8192, 1);
    k_flash<<<dim3(1024), dim3(256), 0, stream>>>(Qb, Kb, Vt2, Ob);
    k_gemm<<<dim3(8, 64), dim3(256), 0, stream>>>(Ob, Wot, bo, 1.0f, nullptr, out, 1024, 0);
}

// Round 7
// 165.425 us; speedup vs baseline: 1.3519x; 1.0907x over previous
//
#include <hip/hip_runtime.h>

typedef unsigned short u16;
typedef __attribute__((ext_vector_type(4))) float f32x4;
typedef __attribute__((ext_vector_type(8))) __bf16 bf16x8;
typedef __attribute__((ext_vector_type(4))) __bf16 bf16x4;
typedef __attribute__((ext_vector_type(4))) unsigned short u16x4;
typedef __attribute__((ext_vector_type(8))) unsigned short u16x8;

// round-to-nearest-even fp32 -> bf16 (used in epilogues / converts)
static __device__ __forceinline__ u16 f2bf(float f) {
    union { float f; unsigned u; } v; v.f = f;
    unsigned r = v.u + 0x7FFFu + ((v.u >> 16) & 1u);
    return (u16)(r >> 16);
}

// v_exp_f32: D = 2^x
static __device__ __forceinline__ float exp2f_fast(float x) {
    float r; asm("v_exp_f32 %0, %1" : "=v"(r) : "v"(x)); return r;
}

// async global->LDS, 16 bytes per lane (dest must be uniform base + lane*16)
static __device__ __forceinline__ void gload16(const u16* g, u16* l) {
    __builtin_amdgcn_global_load_lds(
        (const __attribute__((address_space(1))) unsigned int*)g,
        (__attribute__((address_space(3))) unsigned int*)l, 16, 0, 0);
}

// counted-wait + raw barrier (T4: never drain to 0 in steady state)
#define VMK_BAR(N) asm volatile("s_waitcnt vmcnt(" #N ")\n\ts_barrier" ::: "memory")
#define WAIT_BAR() asm volatile("s_waitcnt vmcnt(0)\n\ts_barrier" ::: "memory")

// swizzled element offset in a [rows][64] u16 tile (128B rows, XOR 16B-chunk by row&7)
#define SWZ64(row, ec) (((row) * 64) + ((((ec) ^ ((row) & 7))) << 3))

// ---------------- fp32 -> bf16 convert (4 elems/thread) ----------------
__global__ __launch_bounds__(256) void k_cvt(const float* __restrict__ in, u16* __restrict__ out) {
    size_t i = (size_t)blockIdx.x * 256 + threadIdx.x;
    float4 v = ((const float4*)in)[i];
    u16x4 o; o[0] = f2bf(v.x); o[1] = f2bf(v.y); o[2] = f2bf(v.z); o[3] = f2bf(v.w);
    *(u16x4*)(out + i * 4) = o;
}

// ---------------- 4x W [K=1024][N=1024] fp32 -> Wt [N][K] bf16 (scaled), one launch ----------------
__global__ __launch_bounds__(256) void k_wtrans4(
    const float* __restrict__ W0, const float* __restrict__ W1,
    const float* __restrict__ W2, const float* __restrict__ W3,
    u16* __restrict__ T0, u16* __restrict__ T1, u16* __restrict__ T2, u16* __restrict__ T3,
    float s0) {
    const float* W; u16* Tt; float sc;
    switch (blockIdx.z) {
        case 0:  W = W0; Tt = T0; sc = s0;  break;
        case 1:  W = W1; Tt = T1; sc = 1.f; break;
        case 2:  W = W2; Tt = T2; sc = 1.f; break;
        default: W = W3; Tt = T3; sc = 1.f; break;
    }
    __shared__ float tile[32][33];
    int n0 = blockIdx.x * 32, k0 = blockIdx.y * 32;
    int tid = threadIdx.x;
    int r = tid >> 3, c = (tid & 7) * 4;
    float4 v = *(const float4*)(W + (size_t)(k0 + r) * 1024 + n0 + c);
    tile[r][c] = v.x; tile[r][c + 1] = v.y; tile[r][c + 2] = v.z; tile[r][c + 3] = v.w;
    __syncthreads();
    u16x4 o;
    o[0] = f2bf(tile[c][r] * sc);
    o[1] = f2bf(tile[c + 1][r] * sc);
    o[2] = f2bf(tile[c + 2][r] * sc);
    o[3] = f2bf(tile[c + 3][r] * sc);
    *(u16x4*)(Tt + (size_t)(n0 + r) * 1024 + k0 + c) = o;
}

// ---------------- shared GEMM main-loop pieces (128x128 tile, BK=32) ----------------
// Triple-buffered 2-deep prefetch with counted vmcnt(4) (T4), T2 XOR-swizzled LDS,
// T5 setprio around the MFMA cluster.
// T2: LDS [row][32] holds global 16B-chunk c at position c ^ ((row>>1)&3); the
// 16 fragment rows then spread over all eight 4-bank slots (2-way residual = free).
static __device__ __forceinline__ void gemm_step(const u16* As, const u16* Bs,
                                                 int wm, int wn, int fr, int gg,
                                                 f32x4 acc[4][4]) {
    const int co = (gg ^ ((fr >> 1) & 3)) * 8;
    bf16x8 af[4], bf[4];
#pragma unroll
    for (int mt = 0; mt < 4; ++mt) af[mt] = *(const bf16x8*)(&As[(wm + mt * 16 + fr) * 32 + co]);
#pragma unroll
    for (int nt = 0; nt < 4; ++nt) bf[nt] = *(const bf16x8*)(&Bs[(wn + nt * 16 + fr) * 32 + co]);
    __builtin_amdgcn_s_setprio(1);
#pragma unroll
    for (int mt = 0; mt < 4; ++mt)
#pragma unroll
        for (int nt = 0; nt < 4; ++nt)
            acc[mt][nt] = __builtin_amdgcn_mfma_f32_16x16x32_bf16(af[mt], bf[nt], acc[mt][nt], 0, 0, 0);
    __builtin_amdgcn_s_setprio(0);
}

#define GEMM_PRELUDE(A_, B_)                                                    \
    const int tid = threadIdx.x;                                                \
    const int l = tid & 63, w = tid >> 6;                                       \
    const int wm = (w >> 1) * 64, wn = (w & 1) * 64;                            \
    const size_t m0 = (size_t)blockIdx.y * 128, n0 = (size_t)blockIdx.x * 128;  \
    const int fr = l & 15, gg = l >> 4, f4 = (l >> 4) * 4;                      \
    const int j0 = w * 2;                                                       \
    const int srow0 = j0 * 16 + (l >> 2), srow1 = srow0 + 16;                   \
    const int scol = ((l & 3) ^ ((l >> 3) & 3)) * 8; /* T2 pre-swizzled src */  \
    const u16* Ag0 = (A_) + (m0 + srow0) * 1024 + scol;                         \
    const u16* Ag1 = (A_) + (m0 + srow1) * 1024 + scol;                         \
    const u16* Bg0 = (B_) + (n0 + srow0) * 1024 + scol;                         \
    const u16* Bg1 = (B_) + (n0 + srow1) * 1024 + scol;                         \
    const int lo0 = j0 * 512 + l * 8, lo1 = (j0 + 1) * 512 + l * 8;

#define GSTAGE(ASB, BSB, kt)            \
    gload16(Ag0 + (kt), (ASB) + lo0);   \
    gload16(Ag1 + (kt), (ASB) + lo1);   \
    gload16(Bg0 + (kt), (BSB) + lo0);   \
    gload16(Bg1 + (kt), (BSB) + lo1)

// K=1024 -> 32 steps of BK=32: prologue 2, 10 statically-unrolled triples, 2-step tail.
// vmcnt(4): only the previous phase's 4 loads may remain in flight -> the buffer we
// are about to compute from has landed. Stage is issued AFTER the barrier so no wave
// can overwrite a buffer another wave is still reading.
#define GEMM_MAINLOOP()                                                       \
    f32x4 acc[4][4] = {};                                                     \
    GSTAGE(As0, Bs0, 0);                                                      \
    GSTAGE(As1, Bs1, 32);                                                     \
    for (int t = 0; t < 10; ++t) {                                            \
        const int kt = 64 + t * 96;                                           \
        VMK_BAR(4); GSTAGE(As2, Bs2, kt);      gemm_step(As0, Bs0, wm, wn, fr, gg, acc); \
        VMK_BAR(4); GSTAGE(As0, Bs0, kt + 32); gemm_step(As1, Bs1, wm, wn, fr, gg, acc); \
        VMK_BAR(4); GSTAGE(As1, Bs1, kt + 64); gemm_step(As2, Bs2, wm, wn, fr, gg, acc); \
    }                                                                         \
    VMK_BAR(4); gemm_step(As0, Bs0, wm, wn, fr, gg, acc);                     \
    VMK_BAR(0); gemm_step(As1, Bs1, wm, wn, fr, gg, acc);

// ---------------- generic GEMM (used for V^T and output projection) ----------------
__global__ __launch_bounds__(256) void k_gemm(const u16* __restrict__ A, const u16* __restrict__ Bt,
                                              const float* __restrict__ bias, float bias_scale,
                                              u16* __restrict__ obf, float* __restrict__ of32,
                                              int ldc, int bias_row) {
    __shared__ u16 As0[128 * 32], Bs0[128 * 32];
    __shared__ u16 As1[128 * 32], Bs1[128 * 32];
    __shared__ u16 As2[128 * 32], Bs2[128 * 32];
    GEMM_PRELUDE(A, Bt)
    GEMM_MAINLOOP()
    // epilogue: C/D layout col=lane&15, row=(lane>>4)*4+r  [HW-verified]
#pragma unroll
    for (int mt = 0; mt < 4; ++mt) {
        float rb_[4];
#pragma unroll
        for (int r = 0; r < 4; ++r)
            rb_[r] = bias_row ? bias[m0 + wm + mt * 16 + f4 + r] * bias_scale : 0.f;
#pragma unroll
        for (int nt = 0; nt < 4; ++nt) {
            const size_t col = n0 + wn + nt * 16 + fr;
            const float cb = bias_row ? 0.f : bias[col] * bias_scale;
#pragma unroll
            for (int r = 0; r < 4; ++r) {
                const size_t row = m0 + wm + mt * 16 + f4 + r;
                const float vv = acc[mt][nt][r] + cb + rb_[r];
                if (of32) of32[row * (size_t)ldc + col] = vv;
                else      obf[row * (size_t)ldc + col] = f2bf(vv);
            }
        }
    }
}

// ---------------- fused Q+K projection: Bt = stacked [Wqt;Wkt] (N=2048), grid (16,64) ----------------
__global__ __launch_bounds__(256) void k_gemmQK(const u16* __restrict__ A, const u16* __restrict__ Wqkt,
                                                const float* __restrict__ bq, const float* __restrict__ bk,
                                                float qscale, u16* __restrict__ Qb, u16* __restrict__ Kb) {
    __shared__ u16 As0[128 * 32], Bs0[128 * 32];
    __shared__ u16 As1[128 * 32], Bs1[128 * 32];
    __shared__ u16 As2[128 * 32], Bs2[128 * 32];
    GEMM_PRELUDE(A, Wqkt)
    GEMM_MAINLOOP()
    const int seg = (int)(n0 >> 10);                 // block-uniform: 0 -> Q, 1 -> K
    const float* bias = seg ? bk : bq;
    const float bsc = seg ? 1.f : qscale;
    u16* ob = seg ? Kb : Qb;
#pragma unroll
    for (int mt = 0; mt < 4; ++mt)
#pragma unroll
        for (int nt = 0; nt < 4; ++nt) {
            const size_t colm = (n0 + wn + nt * 16 + fr) & 1023;
            const float bb = bias[colm] * bsc;
#pragma unroll
            for (int r = 0; r < 4; ++r) {
                const size_t row = m0 + wm + mt * 16 + f4 + r;
                ob[row * 1024 + colm] = f2bf(acc[mt][nt][r] + bb);
            }
        }
}

// ---------------- flash attention ----------------
// Softmax with NO cross-lane ops in the common path: defer-rescale check is a vote on the
// per-lane 16-element max; lsum is a per-lane partial reduced once at the epilogue.
static __device__ __forceinline__ void softmax_grp(const f32x4 s[4], f32x4 o[4],
                                                   float& m, float& lsum, bf16x4 p[4]) {
    float mymax = s[0][0];
#pragma unroll
    for (int nt = 0; nt < 4; ++nt)
#pragma unroll
        for (int r = 0; r < 4; ++r) mymax = fmaxf(mymax, s[nt][r]);
    float ps = 0.f;
#pragma unroll
    for (int nt = 0; nt < 4; ++nt)
#pragma unroll
        for (int r = 0; r < 4; ++r) {
            const float pp = exp2f_fast(s[nt][r]);
            ps += pp; p[nt][r] = (__bf16)pp;
        }
    if (__builtin_expect(__any(mymax > 11.0f), 0)) {   // wave-uniform rare path
        float rm = fmaxf(mymax, __shfl_xor(mymax, 16, 64));
        rm = fmaxf(rm, __shfl_xor(rm, 32, 64));
        const float d = fmaxf(rm, 0.f);
        const float fac = exp2f_fast(-d);
        m += d; lsum *= fac;
#pragma unroll
        for (int mt = 0; mt < 4; ++mt)
#pragma unroll
            for (int r = 0; r < 4; ++r) o[mt][r] *= fac;
        ps = 0.f;
#pragma unroll
        for (int nt = 0; nt < 4; ++nt)
#pragma unroll
            for (int r = 0; r < 4; ++r) {
                const float pp = exp2f_fast(s[nt][r] - d);
                ps += pp; p[nt][r] = (__bf16)pp;
            }
    }
    lsum += ps;
}

static __device__ __forceinline__ void flash_tile(const u16* Ks, const u16* Vs,
                                                  int fr, int gg,
                                                  bf16x8 qA0, bf16x8 qA1, bf16x8 qB0, bf16x8 qB1,
                                                  f32x4 oA[4], f32x4 oB[4],
                                                  float& mA, float& lA, float& mB, float& lB) {
    // S^T = mfma(K, Q) with C-init = -m (log2 domain); lane q = fr, k = nt*16+gg*4+r
    f32x4 sA[4], sB[4];
    __builtin_amdgcn_s_setprio(1);
#pragma unroll
    for (int nt = 0; nt < 4; ++nt) {
        const int rk = nt * 16 + fr;
        const bf16x8 kf0 = *(const bf16x8*)(&Ks[SWZ64(rk, gg)]);
        const bf16x8 kf1 = *(const bf16x8*)(&Ks[SWZ64(rk, gg + 4)]);
        f32x4 z = {-mA, -mA, -mA, -mA};
        z = __builtin_amdgcn_mfma_f32_16x16x32_bf16(kf0, qA0, z, 0, 0, 0);
        z = __builtin_amdgcn_mfma_f32_16x16x32_bf16(kf1, qA1, z, 0, 0, 0);
        sA[nt] = z;
        f32x4 y = {-mB, -mB, -mB, -mB};
        y = __builtin_amdgcn_mfma_f32_16x16x32_bf16(kf0, qB0, y, 0, 0, 0);
        y = __builtin_amdgcn_mfma_f32_16x16x32_bf16(kf1, qB1, y, 0, 0, 0);
        sB[nt] = y;
    }
    __builtin_amdgcn_s_setprio(0);
    bf16x4 pA[4], pB[4];
    softmax_grp(sA, oA, mA, lA, pA);
    softmax_grp(sB, oB, mB, lB, pB);
    // B-fragments straight from registers (k-permutation invariance)
    const bf16x8 BA0 = __builtin_shufflevector(pA[0], pA[1], 0, 1, 2, 3, 4, 5, 6, 7);
    const bf16x8 BA1 = __builtin_shufflevector(pA[2], pA[3], 0, 1, 2, 3, 4, 5, 6, 7);
    const bf16x8 BB0 = __builtin_shufflevector(pB[0], pB[1], 0, 1, 2, 3, 4, 5, 6, 7);
    const bf16x8 BB1 = __builtin_shufflevector(pB[2], pB[3], 0, 1, 2, 3, 4, 5, 6, 7);
    // PV: A-frag reg j = V^T[hd][(j>>2)*16 + gg*4 + (j&3)] (matching permuted k-order)
    const int e0 = gg >> 1, hf = (gg & 1) * 4;
    __builtin_amdgcn_s_setprio(1);
#pragma unroll
    for (int mt = 0; mt < 4; ++mt) {
        const int rv = mt * 16 + fr;
        const int rs = rv & 7, rb = rv * 64;
        const bf16x4 v0 = *(const bf16x4*)(&Vs[rb + (((e0    ) ^ rs) << 3) + hf]);
        const bf16x4 v1 = *(const bf16x4*)(&Vs[rb + (((e0 + 2) ^ rs) << 3) + hf]);
        const bf16x4 v2 = *(const bf16x4*)(&Vs[rb + (((e0 + 4) ^ rs) << 3) + hf]);
        const bf16x4 v3 = *(const bf16x4*)(&Vs[rb + (((e0 + 6) ^ rs) << 3) + hf]);
        const bf16x8 vk0 = __builtin_shufflevector(v0, v1, 0, 1, 2, 3, 4, 5, 6, 7);
        const bf16x8 vk1 = __builtin_shufflevector(v2, v3, 0, 1, 2, 3, 4, 5, 6, 7);
        oA[mt] = __builtin_amdgcn_mfma_f32_16x16x32_bf16(vk0, BA0, oA[mt], 0, 0, 0);
        oA[mt] = __builtin_amdgcn_mfma_f32_16x16x32_bf16(vk1, BA1, oA[mt], 0, 0, 0);
        oB[mt] = __builtin_amdgcn_mfma_f32_16x16x32_bf16(vk0, BB0, oB[mt], 0, 0, 0);
        oB[mt] = __builtin_amdgcn_mfma_f32_16x16x32_bf16(vk1, BB1, oB[mt], 0, 0, 0);
    }
    __builtin_amdgcn_s_setprio(0);
}

// 1D grid 1024 blocks (XCD-bijective swizzle -> K/V L2-resident). 4 waves, 32 q-rows/wave
// (groups A/B). V read directly from Vt2[n_global][t_global] (ld=8192).
// 2-phase double-buffered K/V staging, fused vmcnt(0)+s_barrier per tile.
__global__ __launch_bounds__(256, 2) void k_flash(const u16* __restrict__ Q, const u16* __restrict__ K,
                                                  const u16* __restrict__ Vt2, u16* __restrict__ O) {
    __shared__ u16 Ks0[64 * 64], Vs0[64 * 64];
    __shared__ u16 Ks1[64 * 64], Vs1[64 * 64];
    const int tid = threadIdx.x;
    const int l = tid & 63, w = tid >> 6;
    const int id = blockIdx.x;
    const int swz = (id & 7) * 128 + (id >> 3);      // bijective XCD swizzle (1024 % 8 == 0)
    const int bh = swz >> 3, qt = swz & 7;
    const int b = bh >> 4, h = bh & 15;
    const int qw = qt * 128 + w * 32;
    const int fr = l & 15, gg = l >> 4, f4 = gg * 4, f8 = gg * 8;

    // Q fragments (SCALE*LOG2E folded into Wq/bq)
    const u16* qpA = Q + ((size_t)(b * 1024 + qw + fr)) * 1024 + h * 64 + f8;
    const u16* qpB = qpA + 16 * 1024;
    const bf16x8 qA0 = *(const bf16x8*)qpA;
    const bf16x8 qA1 = *(const bf16x8*)(qpA + 32);
    const bf16x8 qB0 = *(const bf16x8*)qpB;
    const bf16x8 qB1 = *(const bf16x8*)(qpB + 32);

    // staging: chunk j (0..7) = rows j*8..j*8+7; lane l -> row j*8+(l>>3),
    // source 16B-chunk (l&7)^(l>>3) (pre-swizzled source, linear LDS dest)
    const int jj0 = w * 2, jj1 = w * 2 + 1;
    const int sr0 = jj0 * 8 + (l >> 3), sr1 = jj1 * 8 + (l >> 3);
    const int sc = ((l & 7) ^ (l >> 3)) * 8;
    const u16* kg0 = K + ((size_t)(b * 1024 + sr0)) * 1024 + h * 64 + sc;
    const u16* kg1 = K + ((size_t)(b * 1024 + sr1)) * 1024 + h * 64 + sc;
    const u16* vg0 = Vt2 + ((size_t)(h * 64 + sr0)) * 8192 + b * 1024 + sc;
    const u16* vg1 = Vt2 + ((size_t)(h * 64 + sr1)) * 8192 + b * 1024 + sc;
    const int lk0 = jj0 * 512 + l * 8, lk1 = jj1 * 512 + l * 8;

#define FSTAGE(KSB, VSB, kt)                            \
    gload16(kg0 + (size_t)(kt) * 1024, (KSB) + lk0);    \
    gload16(kg1 + (size_t)(kt) * 1024, (KSB) + lk1);    \
    gload16(vg0 + (kt), (VSB) + lk0);                   \
    gload16(vg1 + (kt), (VSB) + lk1)

    f32x4 oA[4] = {}, oB[4] = {};
    float mA = 0.f, lA = 0.f, mB = 0.f, lB = 0.f;   // lA/lB are per-lane partials

    FSTAGE(Ks0, Vs0, 0);
    WAIT_BAR();
    for (int kt0 = 0; kt0 < 1024; kt0 += 128) {
        if (kt0 + 64 < 1024) { FSTAGE(Ks1, Vs1, kt0 + 64); }
        flash_tile(Ks0, Vs0, fr, gg, qA0, qA1, qB0, qB1, oA, oB, mA, lA, mB, lB);
        WAIT_BAR();
        if (kt0 + 128 < 1024) { FSTAGE(Ks0, Vs0, kt0 + 128); }
        flash_tile(Ks1, Vs1, fr, gg, qA0, qA1, qB0, qB1, oA, oB, mA, lA, mB, lB);
        WAIT_BAR();
    }
#undef FSTAGE
    // epilogue: cross-lane lsum reduce (once), then O[t][h*64 + mt*16 + f4 + r]
    lA += __shfl_xor(lA, 16, 64); lA += __shfl_xor(lA, 32, 64);
    lB += __shfl_xor(lB, 16, 64); lB += __shfl_xor(lB, 32, 64);
    const float ivA = 1.0f / lA, ivB = 1.0f / lB;
    u16* opA = O + ((size_t)(b * 1024 + qw + fr)) * 1024 + h * 64;
    u16* opB = opA + 16 * 1024;
#pragma unroll
    for (int mt = 0; mt < 4; ++mt) {
        u16x4 oa, ob;
#pragma unroll
        for (int r = 0; r < 4; ++r) { oa[r] = f2bf(oA[mt][r] * ivA); ob[r] = f2bf(oB[mt][r] * ivB); }
        *(u16x4*)(opA + mt * 16 + f4) = oa;
        *(u16x4*)(opB + mt * 16 + f4) = ob;
    }
}

extern "C" void kernel_launch(void* const* d_in, const int* in_sizes, int n_in,
                              void* d_out, int out_size, void* d_ws, size_t ws_size,
                              hipStream_t stream) {
    (void)in_sizes; (void)n_in; (void)out_size; (void)ws_size;
    const float* hs = (const float*)d_in[0];
    const float* Wq = (const float*)d_in[1];
    const float* bq = (const float*)d_in[2];
    const float* Wk = (const float*)d_in[3];
    const float* bk = (const float*)d_in[4];
    const float* Wv = (const float*)d_in[5];
    const float* bv = (const float*)d_in[6];
    const float* Wo = (const float*)d_in[7];
    const float* bo = (const float*)d_in[8];
    float* out = (float*)d_out;
    char* ws = (char*)d_ws;
    const size_t MB = 1024ull * 1024ull;
    u16* Xb  = (u16*)(ws);            // 16 MB (dead after last GEMM use; reused as attn output Ob)
    u16* Wqt = (u16*)(ws + 16 * MB);  // 2 MB each; Wqt+Wkt adjacent => stacked [2048][1024] for k_gemmQK
    u16* Wkt = (u16*)(ws + 18 * MB);
    u16* Wvt = (u16*)(ws + 20 * MB);
    u16* Wot = (u16*)(ws + 22 * MB);
    u16* Qb  = (u16*)(ws + 24 * MB);  // 16 MB
    u16* Kb  = (u16*)(ws + 40 * MB);  // 16 MB
    u16* Vt2 = (u16*)(ws + 56 * MB);  // 16 MB: V^T[n_global][t_global], ld=8192 -> 72 MB total
    u16* Ob  = Xb;

    // HD^-0.5 * log2(e) folded into Wq and bq (softmax runs in log2 domain)
    const float SCALE_Q = 0.125f * 1.4426950408889634f;

    k_cvt<<<dim3(8192), dim3(256), 0, stream>>>(hs, Xb);
    k_wtrans4<<<dim3(32, 32, 4), dim3(256), 0, stream>>>(Wq, Wk, Wv, Wo, Wqt, Wkt, Wvt, Wot, SCALE_Q);
    // fused Q+K projection: N=2048 over stacked [Wqt;Wkt], 1024 blocks
    k_gemmQK<<<dim3(16, 64), dim3(256), 0, stream>>>(Xb, Wqt, bq, bk, SCALE_Q, Qb, Kb);
    // V^T = Wv^T * X^T : A = Wvt [n][k], Bt = Xb [t][k], C = Vt2 [n][t] (ld 8192), bias per row
    k_gemm<<<dim3(64, 8), dim3(256), 0, stream>>>(Wvt, Xb, bv, 1.0f, Vt2, nullptr, 8192, 1);
    k_flash<<<dim3(1024), dim3(256), 0, stream>>>(Qb, Kb, Vt2, Ob);
    k_gemm<<<dim3(8, 64), dim3(256), 0, stream>>>(Ob, Wot, bo, 1.0f, nullptr, out, 1024, 0);
}

// Round 8
// 155.845 us; speedup vs baseline: 1.4351x; 1.0615x over previous
//
#include <hip/hip_runtime.h>

typedef unsigned short u16;
typedef __attribute__((ext_vector_type(4))) float f32x4;
typedef __attribute__((ext_vector_type(8))) __bf16 bf16x8;
typedef __attribute__((ext_vector_type(4))) __bf16 bf16x4;
typedef __attribute__((ext_vector_type(4))) unsigned short u16x4;
typedef __attribute__((ext_vector_type(8))) unsigned short u16x8;

// round-to-nearest-even fp32 -> bf16 (used in epilogues / converts)
static __device__ __forceinline__ u16 f2bf(float f) {
    union { float f; unsigned u; } v; v.f = f;
    unsigned r = v.u + 0x7FFFu + ((v.u >> 16) & 1u);
    return (u16)(r >> 16);
}

// v_exp_f32: D = 2^x
static __device__ __forceinline__ float exp2f_fast(float x) {
    float r; asm("v_exp_f32 %0, %1" : "=v"(r) : "v"(x)); return r;
}

// async global->LDS, 16 bytes per lane (dest must be wave-uniform base + lane*16)
static __device__ __forceinline__ void gload16(const u16* g, u16* l) {
    __builtin_amdgcn_global_load_lds(
        (const __attribute__((address_space(1))) unsigned int*)g,
        (__attribute__((address_space(3))) unsigned int*)l, 16, 0, 0);
}

#define WAIT_BAR() asm volatile("s_waitcnt vmcnt(0)\n\ts_barrier" ::: "memory")

template<int N> static __device__ __forceinline__ void vm_wait() {
    if constexpr (N >= 8)      asm volatile("s_waitcnt vmcnt(8)" ::: "memory");
    else if constexpr (N == 6) asm volatile("s_waitcnt vmcnt(6)" ::: "memory");
    else if constexpr (N == 4) asm volatile("s_waitcnt vmcnt(4)" ::: "memory");
    else if constexpr (N == 3) asm volatile("s_waitcnt vmcnt(3)" ::: "memory");
    else                       asm volatile("s_waitcnt vmcnt(0)" ::: "memory");
}

// swizzled element offset in a [rows][64] u16 tile (flash K/V tiles)
#define SWZ64(row, ec) (((row) * 64) + ((((ec) ^ ((row) & 7))) << 3))

// ---------------- fp32 -> bf16 convert (4 elems/thread) ----------------
__global__ __launch_bounds__(256) void k_cvt(const float* __restrict__ in, u16* __restrict__ out) {
    size_t i = (size_t)blockIdx.x * 256 + threadIdx.x;
    float4 v = ((const float4*)in)[i];
    u16x4 o; o[0] = f2bf(v.x); o[1] = f2bf(v.y); o[2] = f2bf(v.z); o[3] = f2bf(v.w);
    *(u16x4*)(out + i * 4) = o;
}

// ---------------- 4x W [K=1024][N=1024] fp32 -> Wt [N][K] bf16 (scaled), one launch ----------------
__global__ __launch_bounds__(256) void k_wtrans4(
    const float* __restrict__ W0, const float* __restrict__ W1,
    const float* __restrict__ W2, const float* __restrict__ W3,
    u16* __restrict__ T0, u16* __restrict__ T1, u16* __restrict__ T2, u16* __restrict__ T3,
    float s0) {
    const float* W; u16* Tt; float sc;
    switch (blockIdx.z) {
        case 0:  W = W0; Tt = T0; sc = s0;  break;
        case 1:  W = W1; Tt = T1; sc = 1.f; break;
        case 2:  W = W2; Tt = T2; sc = 1.f; break;
        default: W = W3; Tt = T3; sc = 1.f; break;
    }
    __shared__ float tile[32][33];
    int n0 = blockIdx.x * 32, k0 = blockIdx.y * 32;
    int tid = threadIdx.x;
    int r = tid >> 3, c = (tid & 7) * 4;
    float4 v = *(const float4*)(W + (size_t)(k0 + r) * 1024 + n0 + c);
    tile[r][c] = v.x; tile[r][c + 1] = v.y; tile[r][c + 2] = v.z; tile[r][c + 3] = v.w;
    __syncthreads();
    u16x4 o;
    o[0] = f2bf(tile[c][r] * sc);
    o[1] = f2bf(tile[c + 1][r] * sc);
    o[2] = f2bf(tile[c + 2][r] * sc);
    o[3] = f2bf(tile[c + 3][r] * sc);
    *(u16x4*)(Tt + (size_t)(n0 + r) * 1024 + k0 + c) = o;
}

// ---------------- 256-wide GEMM, m201-style phase schedule ----------------
// BM=256, BK=32, 512 threads (8 waves). BN=256: waves 2M x 4N (wave C = 128x64);
// BN=128: waves 4M x 2N (wave C = 64x64). 4-deep K-tile LDS pipeline, counted
// vmcnt(2L) once per K-tile (L = per-wave loads/tile). Involution swizzle
// chunk ^= (row>>1)&3 on both stage-source and frag-read (2-way residual, free).
// Per phase: {ds_read frags, stage future half-tile, barrier, lgkmcnt(0)+sched_barrier,
// setprio(1), 16 MFMA, setprio(0)}.
template<int BN>
__global__ __launch_bounds__(512, 2) void k_g256(
    const u16* __restrict__ A, const u16* __restrict__ Bt,
    const float* __restrict__ bias, const float* __restrict__ biasK, float qscale,
    u16* __restrict__ obf, u16* __restrict__ obK, float* __restrict__ of32,
    int ldc, int bias_row, int nblk, int mode) {
    constexpr int WN = (BN == 256) ? 4 : 2;       // waves along N
    constexpr int WAVE_M = (BN == 256) ? 128 : 64;
    constexpr int M_REP = WAVE_M / 16;            // 8 or 4
    constexpr int BCALLS = BN / 128;              // 2 or 1
    constexpr int LPT = 2 + BCALLS;               // per-wave gloads per K-tile (4 or 3)
    constexpr int ASLOT = 256 * 32;               // u16 per A K-tile slot (16 KB)
    constexpr int BSLOT = BN * 32;                // u16 per B K-tile slot
    __shared__ u16 As[4 * ASLOT];
    __shared__ u16 Bs[4 * BSLOT];
    const int tid = threadIdx.x;
    const int l = tid & 63, w = tid >> 6;
    const int mw = w / WN, nw = w % WN;
    const int fr = l & 15, gg = l >> 4, f4 = gg * 4;
    // XCD-bijective swizzle (grid is always 256 = 32 per XCD)
    const int id = blockIdx.x;
    const int swz = (id & 7) * 32 + (id >> 3);
    const int bm = swz / nblk, bn = swz % nblk;
    const size_t m0 = (size_t)bm * 256, n0v = (size_t)bn * BN;

    // staging: each 8KB call covers 128 rows; wave w rows w*16..w*16+15 per 2KB..
    // lane l -> row w*16 + (l>>2), LDS pos (l&3); source chunk pre-swizzled so that
    // LDS pos p of row r holds global chunk p ^ ((r>>1)&3).
    const int srow = w * 16 + (l >> 2);
    const int schk = ((l & 3) ^ ((l >> 3) & 3)) * 8;
    const u16* agp0 = A + (m0 + srow) * 1024 + schk;
    const u16* agp1 = A + (m0 + 128 + srow) * 1024 + schk;
    const u16* bgp0 = Bt + (n0v + srow) * 1024 + schk;
    const u16* bgp1 = (BN == 256) ? Bt + (n0v + 128 + srow) * 1024 + schk : bgp0;
    const int ldst = w * 512 + l * 8;   // u16 offset within an 8KB call region

    // fragment read offsets (read-side XOR undoes the store-side XOR -> canonical k)
    const int fchk = (gg ^ ((fr >> 1) & 3)) * 8;
    int aoff[8], boff[4];
#pragma unroll
    for (int mt = 0; mt < 8; ++mt) aoff[mt] = (mw * WAVE_M + mt * 16 + fr) * 32 + fchk;
#pragma unroll
    for (int nt = 0; nt < 4; ++nt) boff[nt] = (nw * 64 + nt * 16 + fr) * 32 + fchk;

    f32x4 acc[8][4] = {};

    // prologue: stage K-tiles 0,1,2 into slots 0,1,2 (per-tile order: A0,A1,B0[,B1])
#define PSTG(S, J)                                                              \
    gload16(agp0 + (size_t)(J) * 32, As + (S) * ASLOT + ldst);                  \
    gload16(agp1 + (size_t)(J) * 32, As + (S) * ASLOT + 4096 + ldst);           \
    gload16(bgp0 + (size_t)(J) * 32, Bs + (S) * BSLOT + ldst);                  \
    if constexpr (BN == 256)                                                    \
        gload16(bgp1 + (size_t)(J) * 32, Bs + (S) * BSLOT + 4096 + ldst);
    PSTG(0, 0) PSTG(1, 1) PSTG(2, 2)
#undef PSTG

#define TILE(S, J, VMN, STG)                                                    \
    {                                                                           \
        vm_wait<VMN>();                                                         \
        __builtin_amdgcn_s_barrier();                                           \
        bf16x8 afr[4], bfr[4];                                                  \
        _Pragma("unroll")                                                       \
        for (int nt = 0; nt < 4; ++nt)                                          \
            bfr[nt] = *(const bf16x8*)(&Bs[(S) * BSLOT + boff[nt]]);            \
        _Pragma("unroll")                                                       \
        for (int mt = 0; mt < 4; ++mt)                                          \
            afr[mt] = *(const bf16x8*)(&As[(S) * ASLOT + aoff[mt]]);            \
        if constexpr (STG) {                                                    \
            gload16(agp0 + (size_t)((J) + 3) * 32, As + (((S) + 3) & 3) * ASLOT + ldst);        \
            gload16(agp1 + (size_t)((J) + 3) * 32, As + (((S) + 3) & 3) * ASLOT + 4096 + ldst); \
            if constexpr (BN == 128)                                            \
                gload16(bgp0 + (size_t)((J) + 3) * 32, Bs + (((S) + 3) & 3) * BSLOT + ldst);    \
        }                                                                       \
        __builtin_amdgcn_s_barrier();                                           \
        asm volatile("s_waitcnt lgkmcnt(0)" ::: "memory");                      \
        __builtin_amdgcn_sched_barrier(0);                                      \
        __builtin_amdgcn_s_setprio(1);                                          \
        _Pragma("unroll")                                                       \
        for (int mt = 0; mt < 4; ++mt)                                          \
            _Pragma("unroll")                                                   \
            for (int nt = 0; nt < 4; ++nt)                                      \
                acc[mt][nt] = __builtin_amdgcn_mfma_f32_16x16x32_bf16(afr[mt], bfr[nt], acc[mt][nt], 0, 0, 0); \
        __builtin_amdgcn_s_setprio(0);                                          \
        if constexpr (BN == 256) {                                              \
            _Pragma("unroll")                                                   \
            for (int mt = 0; mt < 4; ++mt)                                      \
                afr[mt] = *(const bf16x8*)(&As[(S) * ASLOT + aoff[4 + mt]]);    \
            if constexpr (STG) {                                                \
                gload16(bgp0 + (size_t)((J) + 3) * 32, Bs + (((S) + 3) & 3) * BSLOT + ldst);        \
                gload16(bgp1 + (size_t)((J) + 3) * 32, Bs + (((S) + 3) & 3) * BSLOT + 4096 + ldst); \
            }                                                                   \
            __builtin_amdgcn_s_barrier();                                       \
            asm volatile("s_waitcnt lgkmcnt(0)" ::: "memory");                  \
            __builtin_amdgcn_sched_barrier(0);                                  \
            __builtin_amdgcn_s_setprio(1);                                      \
            _Pragma("unroll")                                                   \
            for (int mt = 0; mt < 4; ++mt)                                      \
                _Pragma("unroll")                                               \
                for (int nt = 0; nt < 4; ++nt)                                  \
                    acc[4 + mt][nt] = __builtin_amdgcn_mfma_f32_16x16x32_bf16(afr[mt], bfr[nt], acc[4 + mt][nt], 0, 0, 0); \
            __builtin_amdgcn_s_setprio(0);                                      \
        }                                                                       \
    }

    // K = 1024 -> 32 K-tiles; tiles 0..28 stage T(j+3); tail peeled with reduced vmcnt.
#pragma unroll 1
    for (int jb = 0; jb < 28; jb += 4) {
        TILE(0, jb + 0, (2 * LPT), true)
        TILE(1, jb + 1, (2 * LPT), true)
        TILE(2, jb + 2, (2 * LPT), true)
        TILE(3, jb + 3, (2 * LPT), true)
    }
    TILE(0, 28, (2 * LPT), true)
    TILE(1, 29, (2 * LPT), false)
    TILE(2, 30, LPT, false)
    TILE(3, 31, 0, false)
#undef TILE

    // epilogue: C/D layout col = lane&15, row = (lane>>4)*4 + r  [HW-verified]
    const int mrow0 = (int)m0 + mw * WAVE_M;
    const int ncol0 = (int)n0v + nw * 64;
    if (mode == 1) {   // QK split (BN==256): cols 0..1023 -> Q (bias*qscale), 1024.. -> K
#pragma unroll
        for (int mt = 0; mt < M_REP; ++mt)
#pragma unroll
            for (int nt = 0; nt < 4; ++nt) {
                const int col = ncol0 + nt * 16 + fr;
                const int seg = col >> 10, colm = col & 1023;
                const float bb = (seg ? biasK[colm] : bias[colm] * qscale);
                u16* op = seg ? obK : obf;
#pragma unroll
                for (int r = 0; r < 4; ++r)
                    op[(size_t)(mrow0 + mt * 16 + f4 + r) * 1024 + colm] = f2bf(acc[mt][nt][r] + bb);
            }
    } else {
#pragma unroll
        for (int mt = 0; mt < M_REP; ++mt) {
            float rb_[4];
#pragma unroll
            for (int r = 0; r < 4; ++r)
                rb_[r] = bias_row ? bias[mrow0 + mt * 16 + f4 + r] : 0.f;
#pragma unroll
            for (int nt = 0; nt < 4; ++nt) {
                const int col = ncol0 + nt * 16 + fr;
                const float cb = bias_row ? 0.f : bias[col];
#pragma unroll
                for (int r = 0; r < 4; ++r) {
                    const size_t row = (size_t)(mrow0 + mt * 16 + f4 + r);
                    const float vv = acc[mt][nt][r] + cb + rb_[r];
                    if (of32) of32[row * (size_t)ldc + col] = vv;
                    else      obf[row * (size_t)ldc + col] = f2bf(vv);
                }
            }
        }
    }
}

// ---------------- flash attention (unchanged from round 7) ----------------
static __device__ __forceinline__ void softmax_grp(const f32x4 s[4], f32x4 o[4],
                                                   float& m, float& lsum, bf16x4 p[4]) {
    float mymax = s[0][0];
#pragma unroll
    for (int nt = 0; nt < 4; ++nt)
#pragma unroll
        for (int r = 0; r < 4; ++r) mymax = fmaxf(mymax, s[nt][r]);
    float ps = 0.f;
#pragma unroll
    for (int nt = 0; nt < 4; ++nt)
#pragma unroll
        for (int r = 0; r < 4; ++r) {
            const float pp = exp2f_fast(s[nt][r]);
            ps += pp; p[nt][r] = (__bf16)pp;
        }
    if (__builtin_expect(__any(mymax > 11.0f), 0)) {   // wave-uniform rare path
        float rm = fmaxf(mymax, __shfl_xor(mymax, 16, 64));
        rm = fmaxf(rm, __shfl_xor(rm, 32, 64));
        const float d = fmaxf(rm, 0.f);
        const float fac = exp2f_fast(-d);
        m += d; lsum *= fac;
#pragma unroll
        for (int mt = 0; mt < 4; ++mt)
#pragma unroll
            for (int r = 0; r < 4; ++r) o[mt][r] *= fac;
        ps = 0.f;
#pragma unroll
        for (int nt = 0; nt < 4; ++nt)
#pragma unroll
            for (int r = 0; r < 4; ++r) {
                const float pp = exp2f_fast(s[nt][r] - d);
                ps += pp; p[nt][r] = (__bf16)pp;
            }
    }
    lsum += ps;
}

static __device__ __forceinline__ void flash_tile(const u16* Ks, const u16* Vs,
                                                  int fr, int gg,
                                                  bf16x8 qA0, bf16x8 qA1, bf16x8 qB0, bf16x8 qB1,
                                                  f32x4 oA[4], f32x4 oB[4],
                                                  float& mA, float& lA, float& mB, float& lB) {
    f32x4 sA[4], sB[4];
    __builtin_amdgcn_s_setprio(1);
#pragma unroll
    for (int nt = 0; nt < 4; ++nt) {
        const int rk = nt * 16 + fr;
        const bf16x8 kf0 = *(const bf16x8*)(&Ks[SWZ64(rk, gg)]);
        const bf16x8 kf1 = *(const bf16x8*)(&Ks[SWZ64(rk, gg + 4)]);
        f32x4 z = {-mA, -mA, -mA, -mA};
        z = __builtin_amdgcn_mfma_f32_16x16x32_bf16(kf0, qA0, z, 0, 0, 0);
        z = __builtin_amdgcn_mfma_f32_16x16x32_bf16(kf1, qA1, z, 0, 0, 0);
        sA[nt] = z;
        f32x4 y = {-mB, -mB, -mB, -mB};
        y = __builtin_amdgcn_mfma_f32_16x16x32_bf16(kf0, qB0, y, 0, 0, 0);
        y = __builtin_amdgcn_mfma_f32_16x16x32_bf16(kf1, qB1, y, 0, 0, 0);
        sB[nt] = y;
    }
    __builtin_amdgcn_s_setprio(0);
    bf16x4 pA[4], pB[4];
    softmax_grp(sA, oA, mA, lA, pA);
    softmax_grp(sB, oB, mB, lB, pB);
    const bf16x8 BA0 = __builtin_shufflevector(pA[0], pA[1], 0, 1, 2, 3, 4, 5, 6, 7);
    const bf16x8 BA1 = __builtin_shufflevector(pA[2], pA[3], 0, 1, 2, 3, 4, 5, 6, 7);
    const bf16x8 BB0 = __builtin_shufflevector(pB[0], pB[1], 0, 1, 2, 3, 4, 5, 6, 7);
    const bf16x8 BB1 = __builtin_shufflevector(pB[2], pB[3], 0, 1, 2, 3, 4, 5, 6, 7);
    const int e0 = gg >> 1, hf = (gg & 1) * 4;
    __builtin_amdgcn_s_setprio(1);
#pragma unroll
    for (int mt = 0; mt < 4; ++mt) {
        const int rv = mt * 16 + fr;
        const int rs = rv & 7, rb = rv * 64;
        const bf16x4 v0 = *(const bf16x4*)(&Vs[rb + (((e0    ) ^ rs) << 3) + hf]);
        const bf16x4 v1 = *(const bf16x4*)(&Vs[rb + (((e0 + 2) ^ rs) << 3) + hf]);
        const bf16x4 v2 = *(const bf16x4*)(&Vs[rb + (((e0 + 4) ^ rs) << 3) + hf]);
        const bf16x4 v3 = *(const bf16x4*)(&Vs[rb + (((e0 + 6) ^ rs) << 3) + hf]);
        const bf16x8 vk0 = __builtin_shufflevector(v0, v1, 0, 1, 2, 3, 4, 5, 6, 7);
        const bf16x8 vk1 = __builtin_shufflevector(v2, v3, 0, 1, 2, 3, 4, 5, 6, 7);
        oA[mt] = __builtin_amdgcn_mfma_f32_16x16x32_bf16(vk0, BA0, oA[mt], 0, 0, 0);
        oA[mt] = __builtin_amdgcn_mfma_f32_16x16x32_bf16(vk1, BA1, oA[mt], 0, 0, 0);
        oB[mt] = __builtin_amdgcn_mfma_f32_16x16x32_bf16(vk0, BB0, oB[mt], 0, 0, 0);
        oB[mt] = __builtin_amdgcn_mfma_f32_16x16x32_bf16(vk1, BB1, oB[mt], 0, 0, 0);
    }
    __builtin_amdgcn_s_setprio(0);
}

__global__ __launch_bounds__(256, 2) void k_flash(const u16* __restrict__ Q, const u16* __restrict__ K,
                                                  const u16* __restrict__ Vt2, u16* __restrict__ O) {
    __shared__ u16 Ks0[64 * 64], Vs0[64 * 64];
    __shared__ u16 Ks1[64 * 64], Vs1[64 * 64];
    const int tid = threadIdx.x;
    const int l = tid & 63, w = tid >> 6;
    const int id = blockIdx.x;
    const int swz = (id & 7) * 128 + (id >> 3);      // bijective XCD swizzle (1024 % 8 == 0)
    const int bh = swz >> 3, qt = swz & 7;
    const int b = bh >> 4, h = bh & 15;
    const int qw = qt * 128 + w * 32;
    const int fr = l & 15, gg = l >> 4, f4 = gg * 4, f8 = gg * 8;

    const u16* qpA = Q + ((size_t)(b * 1024 + qw + fr)) * 1024 + h * 64 + f8;
    const u16* qpB = qpA + 16 * 1024;
    const bf16x8 qA0 = *(const bf16x8*)qpA;
    const bf16x8 qA1 = *(const bf16x8*)(qpA + 32);
    const bf16x8 qB0 = *(const bf16x8*)qpB;
    const bf16x8 qB1 = *(const bf16x8*)(qpB + 32);

    const int jj0 = w * 2, jj1 = w * 2 + 1;
    const int sr0 = jj0 * 8 + (l >> 3), sr1 = jj1 * 8 + (l >> 3);
    const int sc = ((l & 7) ^ (l >> 3)) * 8;
    const u16* kg0 = K + ((size_t)(b * 1024 + sr0)) * 1024 + h * 64 + sc;
    const u16* kg1 = K + ((size_t)(b * 1024 + sr1)) * 1024 + h * 64 + sc;
    const u16* vg0 = Vt2 + ((size_t)(h * 64 + sr0)) * 8192 + b * 1024 + sc;
    const u16* vg1 = Vt2 + ((size_t)(h * 64 + sr1)) * 8192 + b * 1024 + sc;
    const int lk0 = jj0 * 512 + l * 8, lk1 = jj1 * 512 + l * 8;

#define FSTAGE(KSB, VSB, kt)                            \
    gload16(kg0 + (size_t)(kt) * 1024, (KSB) + lk0);    \
    gload16(kg1 + (size_t)(kt) * 1024, (KSB) + lk1);    \
    gload16(vg0 + (kt), (VSB) + lk0);                   \
    gload16(vg1 + (kt), (VSB) + lk1)

    f32x4 oA[4] = {}, oB[4] = {};
    float mA = 0.f, lA = 0.f, mB = 0.f, lB = 0.f;   // lA/lB are per-lane partials

    FSTAGE(Ks0, Vs0, 0);
    WAIT_BAR();
    for (int kt0 = 0; kt0 < 1024; kt0 += 128) {
        if (kt0 + 64 < 1024) { FSTAGE(Ks1, Vs1, kt0 + 64); }
        flash_tile(Ks0, Vs0, fr, gg, qA0, qA1, qB0, qB1, oA, oB, mA, lA, mB, lB);
        WAIT_BAR();
        if (kt0 + 128 < 1024) { FSTAGE(Ks0, Vs0, kt0 + 128); }
        flash_tile(Ks1, Vs1, fr, gg, qA0, qA1, qB0, qB1, oA, oB, mA, lA, mB, lB);
        WAIT_BAR();
    }
#undef FSTAGE
    lA += __shfl_xor(lA, 16, 64); lA += __shfl_xor(lA, 32, 64);
    lB += __shfl_xor(lB, 16, 64); lB += __shfl_xor(lB, 32, 64);
    const float ivA = 1.0f / lA, ivB = 1.0f / lB;
    u16* opA = O + ((size_t)(b * 1024 + qw + fr)) * 1024 + h * 64;
    u16* opB = opA + 16 * 1024;
#pragma unroll
    for (int mt = 0; mt < 4; ++mt) {
        u16x4 oa, ob;
#pragma unroll
        for (int r = 0; r < 4; ++r) { oa[r] = f2bf(oA[mt][r] * ivA); ob[r] = f2bf(oB[mt][r] * ivB); }
        *(u16x4*)(opA + mt * 16 + f4) = oa;
        *(u16x4*)(opB + mt * 16 + f4) = ob;
    }
}

extern "C" void kernel_launch(void* const* d_in, const int* in_sizes, int n_in,
                              void* d_out, int out_size, void* d_ws, size_t ws_size,
                              hipStream_t stream) {
    (void)in_sizes; (void)n_in; (void)out_size; (void)ws_size;
    const float* hs = (const float*)d_in[0];
    const float* Wq = (const float*)d_in[1];
    const float* bq = (const float*)d_in[2];
    const float* Wk = (const float*)d_in[3];
    const float* bk = (const float*)d_in[4];
    const float* Wv = (const float*)d_in[5];
    const float* bv = (const float*)d_in[6];
    const float* Wo = (const float*)d_in[7];
    const float* bo = (const float*)d_in[8];
    float* out = (float*)d_out;
    char* ws = (char*)d_ws;
    const size_t MB = 1024ull * 1024ull;
    u16* Xb  = (u16*)(ws);            // 16 MB (dead after V^T GEMM; reused as attn output Ob)
    u16* Wqt = (u16*)(ws + 16 * MB);  // 2 MB each; Wqt+Wkt adjacent => stacked [2048][1024]
    u16* Wkt = (u16*)(ws + 18 * MB);
    u16* Wvt = (u16*)(ws + 20 * MB);
    u16* Wot = (u16*)(ws + 22 * MB);
    u16* Qb  = (u16*)(ws + 24 * MB);  // 16 MB
    u16* Kb  = (u16*)(ws + 40 * MB);  // 16 MB
    u16* Vt2 = (u16*)(ws + 56 * MB);  // 16 MB: V^T[n_global][t_global], ld=8192 -> 72 MB total
    u16* Ob  = Xb;

    // HD^-0.5 * log2(e) folded into Wq and bq (softmax runs in log2 domain)
    const float SCALE_Q = 0.125f * 1.4426950408889634f;

    k_cvt<<<dim3(8192), dim3(256), 0, stream>>>(hs, Xb);
    k_wtrans4<<<dim3(32, 32, 4), dim3(256), 0, stream>>>(Wq, Wk, Wv, Wo, Wqt, Wkt, Wvt, Wot, SCALE_Q);
    // fused Q+K projection: M=8192, N=2048 over stacked [Wqt;Wkt]; 32x8 = 256 blocks (1/CU)
    k_g256<256><<<dim3(256), dim3(512), 0, stream>>>(Xb, Wqt, bq, bk, SCALE_Q,
                                                     Qb, Kb, nullptr, 1024, 0, 8, 1);
    // V^T = Wv^T * X^T : A = Wvt (M=1024), Bt = Xb (N=8192); 4x64 = 256 blocks; bias per row
    k_g256<128><<<dim3(256), dim3(512), 0, stream>>>(Wvt, Xb, bv, nullptr, 1.f,
                                                     Vt2, nullptr, nullptr, 8192, 1, 64, 0);
    k_flash<<<dim3(1024), dim3(256), 0, stream>>>(Qb, Kb, Vt2, Ob);
    // output projection: M=8192, N=1024, f32 out; 32x8 = 256 blocks
    k_g256<128><<<dim3(256), dim3(512), 0, stream>>>(Ob, Wot, bo, nullptr, 1.f,
                                                     nullptr, nullptr, out, 1024, 0, 8, 0);
}

// Round 9
// 150.788 us; speedup vs baseline: 1.4832x; 1.0335x over previous
//
#include <hip/hip_runtime.h>

typedef unsigned short u16;
typedef __attribute__((ext_vector_type(4))) float f32x4;
typedef __attribute__((ext_vector_type(8))) __bf16 bf16x8;
typedef __attribute__((ext_vector_type(4))) __bf16 bf16x4;
typedef __attribute__((ext_vector_type(4))) unsigned short u16x4;
typedef __attribute__((ext_vector_type(8))) unsigned short u16x8;

// round-to-nearest-even fp32 -> bf16 (used in epilogues / converts)
static __device__ __forceinline__ u16 f2bf(float f) {
    union { float f; unsigned u; } v; v.f = f;
    unsigned r = v.u + 0x7FFFu + ((v.u >> 16) & 1u);
    return (u16)(r >> 16);
}

// v_exp_f32: D = 2^x
static __device__ __forceinline__ float exp2f_fast(float x) {
    float r; asm("v_exp_f32 %0, %1" : "=v"(r) : "v"(x)); return r;
}

// async global->LDS, 16 bytes per lane (dest must be wave-uniform base + lane*16)
static __device__ __forceinline__ void gload16(const u16* g, u16* l) {
    __builtin_amdgcn_global_load_lds(
        (const __attribute__((address_space(1))) unsigned int*)g,
        (__attribute__((address_space(3))) unsigned int*)l, 16, 0, 0);
}

template<int N> static __device__ __forceinline__ void vm_wait() {
    if constexpr (N >= 8)      asm volatile("s_waitcnt vmcnt(8)" ::: "memory");
    else if constexpr (N == 6) asm volatile("s_waitcnt vmcnt(6)" ::: "memory");
    else if constexpr (N == 4) asm volatile("s_waitcnt vmcnt(4)" ::: "memory");
    else if constexpr (N == 3) asm volatile("s_waitcnt vmcnt(3)" ::: "memory");
    else                       asm volatile("s_waitcnt vmcnt(0)" ::: "memory");
}

// swizzled element offset in a [rows][64] u16 tile (flash K/V tiles)
#define SWZ64(row, ec) (((row) * 64) + ((((ec) ^ ((row) & 7))) << 3))

// ---------------- fp32 -> bf16 convert (4 elems/thread) ----------------
__global__ __launch_bounds__(256) void k_cvt(const float* __restrict__ in, u16* __restrict__ out) {
    size_t i = (size_t)blockIdx.x * 256 + threadIdx.x;
    float4 v = ((const float4*)in)[i];
    u16x4 o; o[0] = f2bf(v.x); o[1] = f2bf(v.y); o[2] = f2bf(v.z); o[3] = f2bf(v.w);
    *(u16x4*)(out + i * 4) = o;
}

// ---------------- 4x W [K=1024][N=1024] fp32 -> Wt [N][K] bf16 (scaled), one launch ----------------
__global__ __launch_bounds__(256) void k_wtrans4(
    const float* __restrict__ W0, const float* __restrict__ W1,
    const float* __restrict__ W2, const float* __restrict__ W3,
    u16* __restrict__ T0, u16* __restrict__ T1, u16* __restrict__ T2, u16* __restrict__ T3,
    float s0) {
    const float* W; u16* Tt; float sc;
    switch (blockIdx.z) {
        case 0:  W = W0; Tt = T0; sc = s0;  break;
        case 1:  W = W1; Tt = T1; sc = 1.f; break;
        case 2:  W = W2; Tt = T2; sc = 1.f; break;
        default: W = W3; Tt = T3; sc = 1.f; break;
    }
    __shared__ float tile[32][33];
    int n0 = blockIdx.x * 32, k0 = blockIdx.y * 32;
    int tid = threadIdx.x;
    int r = tid >> 3, c = (tid & 7) * 4;
    float4 v = *(const float4*)(W + (size_t)(k0 + r) * 1024 + n0 + c);
    tile[r][c] = v.x; tile[r][c + 1] = v.y; tile[r][c + 2] = v.z; tile[r][c + 3] = v.w;
    __syncthreads();
    u16x4 o;
    o[0] = f2bf(tile[c][r] * sc);
    o[1] = f2bf(tile[c + 1][r] * sc);
    o[2] = f2bf(tile[c + 2][r] * sc);
    o[3] = f2bf(tile[c + 3][r] * sc);
    *(u16x4*)(Tt + (size_t)(n0 + r) * 1024 + k0 + c) = o;
}

// ---------------- 256-wide GEMM, m201-style phase schedule ----------------
// BM=256, BK=32, 512 threads (8 waves). BN=256: waves 2M x 4N; BN=128: 4M x 2N.
// 4-deep K-tile LDS pipeline, counted vmcnt once per K-tile. Involution swizzle
// chunk ^= (row>>1)&3 on both stage-source and frag-read.
// mode 0: generic (col or row bias). mode 1: QK split. mode 2: V^T with in-32
// column permutation pos = g*8+hi*4+r (g=(t>>2)&3, hi=(t>>4)&1, r=t&3) so flash
// PV A-frags become contiguous b128 reads in the register-P k-order; row bias.
template<int BN>
__global__ __launch_bounds__(512, 2) void k_g256(
    const u16* __restrict__ A, const u16* __restrict__ Bt,
    const float* __restrict__ bias, const float* __restrict__ biasK, float qscale,
    u16* __restrict__ obf, u16* __restrict__ obK, float* __restrict__ of32,
    int ldc, int bias_row, int nblk, int mode) {
    constexpr int WN = (BN == 256) ? 4 : 2;       // waves along N
    constexpr int WAVE_M = (BN == 256) ? 128 : 64;
    constexpr int M_REP = WAVE_M / 16;            // 8 or 4
    constexpr int BCALLS = BN / 128;              // 2 or 1
    constexpr int LPT = 2 + BCALLS;               // per-wave gloads per K-tile (4 or 3)
    constexpr int ASLOT = 256 * 32;               // u16 per A K-tile slot (16 KB)
    constexpr int BSLOT = BN * 32;                // u16 per B K-tile slot
    __shared__ u16 As[4 * ASLOT];
    __shared__ u16 Bs[4 * BSLOT];
    const int tid = threadIdx.x;
    const int l = tid & 63, w = tid >> 6;
    const int mw = w / WN, nw = w % WN;
    const int fr = l & 15, gg = l >> 4, f4 = gg * 4;
    // XCD-bijective swizzle (grid is always 256 = 32 per XCD)
    const int id = blockIdx.x;
    const int swz = (id & 7) * 32 + (id >> 3);
    const int bm = swz / nblk, bn = swz % nblk;
    const size_t m0 = (size_t)bm * 256, n0v = (size_t)bn * BN;

    const int srow = w * 16 + (l >> 2);
    const int schk = ((l & 3) ^ ((l >> 3) & 3)) * 8;
    const u16* agp0 = A + (m0 + srow) * 1024 + schk;
    const u16* agp1 = A + (m0 + 128 + srow) * 1024 + schk;
    const u16* bgp0 = Bt + (n0v + srow) * 1024 + schk;
    const u16* bgp1 = (BN == 256) ? Bt + (n0v + 128 + srow) * 1024 + schk : bgp0;
    const int ldst = w * 512 + l * 8;   // u16 offset within an 8KB call region

    // fragment read offsets (read-side XOR undoes the store-side XOR -> canonical k)
    const int fchk = (gg ^ ((fr >> 1) & 3)) * 8;
    int aoff[8], boff[4];
#pragma unroll
    for (int mt = 0; mt < 8; ++mt) aoff[mt] = (mw * WAVE_M + mt * 16 + fr) * 32 + fchk;
#pragma unroll
    for (int nt = 0; nt < 4; ++nt) boff[nt] = (nw * 64 + nt * 16 + fr) * 32 + fchk;

    f32x4 acc[8][4] = {};

#define PSTG(S, J)                                                              \
    gload16(agp0 + (size_t)(J) * 32, As + (S) * ASLOT + ldst);                  \
    gload16(agp1 + (size_t)(J) * 32, As + (S) * ASLOT + 4096 + ldst);           \
    gload16(bgp0 + (size_t)(J) * 32, Bs + (S) * BSLOT + ldst);                  \
    if constexpr (BN == 256)                                                    \
        gload16(bgp1 + (size_t)(J) * 32, Bs + (S) * BSLOT + 4096 + ldst);
    PSTG(0, 0) PSTG(1, 1) PSTG(2, 2)
#undef PSTG

#define TILE(S, J, VMN, STG)                                                    \
    {                                                                           \
        vm_wait<VMN>();                                                         \
        __builtin_amdgcn_s_barrier();                                           \
        bf16x8 afr[4], bfr[4];                                                  \
        _Pragma("unroll")                                                       \
        for (int nt = 0; nt < 4; ++nt)                                          \
            bfr[nt] = *(const bf16x8*)(&Bs[(S) * BSLOT + boff[nt]]);            \
        _Pragma("unroll")                                                       \
        for (int mt = 0; mt < 4; ++mt)                                          \
            afr[mt] = *(const bf16x8*)(&As[(S) * ASLOT + aoff[mt]]);            \
        if constexpr (STG) {                                                    \
            gload16(agp0 + (size_t)((J) + 3) * 32, As + (((S) + 3) & 3) * ASLOT + ldst);        \
            gload16(agp1 + (size_t)((J) + 3) * 32, As + (((S) + 3) & 3) * ASLOT + 4096 + ldst); \
            if constexpr (BN == 128)                                            \
                gload16(bgp0 + (size_t)((J) + 3) * 32, Bs + (((S) + 3) & 3) * BSLOT + ldst);    \
        }                                                                       \
        __builtin_amdgcn_s_barrier();                                           \
        asm volatile("s_waitcnt lgkmcnt(0)" ::: "memory");                      \
        __builtin_amdgcn_sched_barrier(0);                                      \
        __builtin_amdgcn_s_setprio(1);                                          \
        _Pragma("unroll")                                                       \
        for (int mt = 0; mt < 4; ++mt)                                          \
            _Pragma("unroll")                                                   \
            for (int nt = 0; nt < 4; ++nt)                                      \
                acc[mt][nt] = __builtin_amdgcn_mfma_f32_16x16x32_bf16(afr[mt], bfr[nt], acc[mt][nt], 0, 0, 0); \
        __builtin_amdgcn_s_setprio(0);                                          \
        if constexpr (BN == 256) {                                              \
            _Pragma("unroll")                                                   \
            for (int mt = 0; mt < 4; ++mt)                                      \
                afr[mt] = *(const bf16x8*)(&As[(S) * ASLOT + aoff[4 + mt]]);    \
            if constexpr (STG) {                                                \
                gload16(bgp0 + (size_t)((J) + 3) * 32, Bs + (((S) + 3) & 3) * BSLOT + ldst);        \
                gload16(bgp1 + (size_t)((J) + 3) * 32, Bs + (((S) + 3) & 3) * BSLOT + 4096 + ldst); \
            }                                                                   \
            __builtin_amdgcn_s_barrier();                                       \
            asm volatile("s_waitcnt lgkmcnt(0)" ::: "memory");                  \
            __builtin_amdgcn_sched_barrier(0);                                  \
            __builtin_amdgcn_s_setprio(1);                                      \
            _Pragma("unroll")                                                   \
            for (int mt = 0; mt < 4; ++mt)                                      \
                _Pragma("unroll")                                               \
                for (int nt = 0; nt < 4; ++nt)                                  \
                    acc[4 + mt][nt] = __builtin_amdgcn_mfma_f32_16x16x32_bf16(afr[mt], bfr[nt], acc[4 + mt][nt], 0, 0, 0); \
            __builtin_amdgcn_s_setprio(0);                                      \
        }                                                                       \
    }

#pragma unroll 1
    for (int jb = 0; jb < 28; jb += 4) {
        TILE(0, jb + 0, (2 * LPT), true)
        TILE(1, jb + 1, (2 * LPT), true)
        TILE(2, jb + 2, (2 * LPT), true)
        TILE(3, jb + 3, (2 * LPT), true)
    }
    TILE(0, 28, (2 * LPT), true)
    TILE(1, 29, (2 * LPT), false)
    TILE(2, 30, LPT, false)
    TILE(3, 31, 0, false)
#undef TILE

    // epilogue: C/D layout col = lane&15, row = (lane>>4)*4 + r  [HW-verified]
    const int mrow0 = (int)m0 + mw * WAVE_M;
    const int ncol0 = (int)n0v + nw * 64;
    if (mode == 1) {   // QK split (BN==256): cols 0..1023 -> Q (bias*qscale), 1024.. -> K
#pragma unroll
        for (int mt = 0; mt < M_REP; ++mt)
#pragma unroll
            for (int nt = 0; nt < 4; ++nt) {
                const int col = ncol0 + nt * 16 + fr;
                const int seg = col >> 10, colm = col & 1023;
                const float bb = (seg ? biasK[colm] : bias[colm] * qscale);
                u16* op = seg ? obK : obf;
#pragma unroll
                for (int r = 0; r < 4; ++r)
                    op[(size_t)(mrow0 + mt * 16 + f4 + r) * 1024 + colm] = f2bf(acc[mt][nt][r] + bb);
            }
    } else if (mode == 2) {   // V^T: row bias, in-32 column permutation for flash PV b128
#pragma unroll
        for (int mt = 0; mt < M_REP; ++mt) {
            float rb_[4];
#pragma unroll
            for (int r = 0; r < 4; ++r) rb_[r] = bias[mrow0 + mt * 16 + f4 + r];
#pragma unroll
            for (int nt = 0; nt < 4; ++nt) {
                const int col = ncol0 + nt * 16 + fr;
                const int colp = (col & ~31) | (((col >> 2) & 3) << 3) |
                                 (((col >> 4) & 1) << 2) | (col & 3);
#pragma unroll
                for (int r = 0; r < 4; ++r) {
                    const size_t row = (size_t)(mrow0 + mt * 16 + f4 + r);
                    obf[row * (size_t)ldc + colp] = f2bf(acc[mt][nt][r] + rb_[r]);
                }
            }
        }
    } else {
#pragma unroll
        for (int mt = 0; mt < M_REP; ++mt) {
            float rb_[4];
#pragma unroll
            for (int r = 0; r < 4; ++r)
                rb_[r] = bias_row ? bias[mrow0 + mt * 16 + f4 + r] : 0.f;
#pragma unroll
            for (int nt = 0; nt < 4; ++nt) {
                const int col = ncol0 + nt * 16 + fr;
                const float cb = bias_row ? 0.f : bias[col];
#pragma unroll
                for (int r = 0; r < 4; ++r) {
                    const size_t row = (size_t)(mrow0 + mt * 16 + f4 + r);
                    const float vv = acc[mt][nt][r] + cb + rb_[r];
                    if (of32) of32[row * (size_t)ldc + col] = vv;
                    else      obf[row * (size_t)ldc + col] = f2bf(vv);
                }
            }
        }
    }
}

// ---------------- flash attention: T15 lag-1 PV pipeline ----------------
static __device__ __forceinline__ void qk_tile(const u16* Ks, int fr, int gg,
                                               bf16x8 qA0, bf16x8 qA1, bf16x8 qB0, bf16x8 qB1,
                                               float mA, float mB, f32x4 sA[4], f32x4 sB[4]) {
    __builtin_amdgcn_s_setprio(1);
#pragma unroll
    for (int nt = 0; nt < 4; ++nt) {
        const int rk = nt * 16 + fr;
        const bf16x8 kf0 = *(const bf16x8*)(&Ks[SWZ64(rk, gg)]);
        const bf16x8 kf1 = *(const bf16x8*)(&Ks[SWZ64(rk, gg + 4)]);
        f32x4 z = {-mA, -mA, -mA, -mA};
        z = __builtin_amdgcn_mfma_f32_16x16x32_bf16(kf0, qA0, z, 0, 0, 0);
        z = __builtin_amdgcn_mfma_f32_16x16x32_bf16(kf1, qA1, z, 0, 0, 0);
        sA[nt] = z;
        f32x4 y = {-mB, -mB, -mB, -mB};
        y = __builtin_amdgcn_mfma_f32_16x16x32_bf16(kf0, qB0, y, 0, 0, 0);
        y = __builtin_amdgcn_mfma_f32_16x16x32_bf16(kf1, qB1, y, 0, 0, 0);
        sB[nt] = y;
    }
    __builtin_amdgcn_s_setprio(0);
}

// softmax with no cross-lane ops in the common path (per-lane partial lsum)
static __device__ __forceinline__ void sm_tile(const f32x4 s[4], f32x4 o[4],
                                               float& m, float& lsum, bf16x4 p[4]) {
    float mymax = s[0][0];
#pragma unroll
    for (int nt = 0; nt < 4; ++nt)
#pragma unroll
        for (int r = 0; r < 4; ++r) mymax = fmaxf(mymax, s[nt][r]);
    float ps = 0.f;
#pragma unroll
    for (int nt = 0; nt < 4; ++nt)
#pragma unroll
        for (int r = 0; r < 4; ++r) {
            const float pp = exp2f_fast(s[nt][r]);
            ps += pp; p[nt][r] = (__bf16)pp;
        }
    if (__builtin_expect(__any(mymax > 11.0f), 0)) {   // wave-uniform rare path
        float rm = fmaxf(mymax, __shfl_xor(mymax, 16, 64));
        rm = fmaxf(rm, __shfl_xor(rm, 32, 64));
        const float d = fmaxf(rm, 0.f);
        const float fac = exp2f_fast(-d);
        m += d; lsum *= fac;
#pragma unroll
        for (int mt = 0; mt < 4; ++mt)
#pragma unroll
            for (int r = 0; r < 4; ++r) o[mt][r] *= fac;
        ps = 0.f;
#pragma unroll
        for (int nt = 0; nt < 4; ++nt)
#pragma unroll
            for (int r = 0; r < 4; ++r) {
                const float pp = exp2f_fast(s[nt][r] - d);
                ps += pp; p[nt][r] = (__bf16)pp;
            }
    }
    lsum += ps;
}

// PV with b128 V-frag reads (Vt2 stored k-permuted so register-P k-order is contiguous)
static __device__ __forceinline__ void pv_tile(const u16* Vs, int fr, int gg,
                                               const bf16x4 pA[4], const bf16x4 pB[4],
                                               f32x4 oA[4], f32x4 oB[4]) {
    const bf16x8 BA0 = __builtin_shufflevector(pA[0], pA[1], 0, 1, 2, 3, 4, 5, 6, 7);
    const bf16x8 BA1 = __builtin_shufflevector(pA[2], pA[3], 0, 1, 2, 3, 4, 5, 6, 7);
    const bf16x8 BB0 = __builtin_shufflevector(pB[0], pB[1], 0, 1, 2, 3, 4, 5, 6, 7);
    const bf16x8 BB1 = __builtin_shufflevector(pB[2], pB[3], 0, 1, 2, 3, 4, 5, 6, 7);
    __builtin_amdgcn_s_setprio(1);
#pragma unroll
    for (int mt = 0; mt < 4; ++mt) {
        const int rv = mt * 16 + fr;
        const bf16x8 vk0 = *(const bf16x8*)(&Vs[SWZ64(rv, gg)]);
        const bf16x8 vk1 = *(const bf16x8*)(&Vs[SWZ64(rv, gg + 4)]);
        oA[mt] = __builtin_amdgcn_mfma_f32_16x16x32_bf16(vk0, BA0, oA[mt], 0, 0, 0);
        oA[mt] = __builtin_amdgcn_mfma_f32_16x16x32_bf16(vk1, BA1, oA[mt], 0, 0, 0);
        oB[mt] = __builtin_amdgcn_mfma_f32_16x16x32_bf16(vk0, BB0, oB[mt], 0, 0, 0);
        oB[mt] = __builtin_amdgcn_mfma_f32_16x16x32_bf16(vk1, BB1, oB[mt], 0, 0, 0);
    }
    __builtin_amdgcn_s_setprio(0);
}

// 1D grid 1024 blocks (XCD-bijective swizzle). 4 waves, 32 q-rows/wave (groups A/B).
// 4-slot LDS rotation, counted vmcnt(4) per tile (drain only at tail). Per tile t:
// wait slot t -> barrier -> QK(t) -> stage(t+2) -> PV(t-1) [MFMA] || SM(t) [VALU] -> save P(t).
// PV(t-1) is independent of SM(t), so the exp/cvt latency hides under PV's MFMAs.
__global__ __launch_bounds__(256, 2) void k_flash(const u16* __restrict__ Q, const u16* __restrict__ K,
                                                  const u16* __restrict__ Vt2, u16* __restrict__ O) {
    __shared__ u16 Ks[4][64 * 64];
    __shared__ u16 Vs[4][64 * 64];
    const int tid = threadIdx.x;
    const int l = tid & 63, w = tid >> 6;
    const int id = blockIdx.x;
    const int swz = (id & 7) * 128 + (id >> 3);      // bijective XCD swizzle (1024 % 8 == 0)
    const int bh = swz >> 3, qt = swz & 7;
    const int b = bh >> 4, h = bh & 15;
    const int qw = qt * 128 + w * 32;
    const int fr = l & 15, gg = l >> 4, f4 = gg * 4, f8 = gg * 8;

    const u16* qpA = Q + ((size_t)(b * 1024 + qw + fr)) * 1024 + h * 64 + f8;
    const u16* qpB = qpA + 16 * 1024;
    const bf16x8 qA0 = *(const bf16x8*)qpA;
    const bf16x8 qA1 = *(const bf16x8*)(qpA + 32);
    const bf16x8 qB0 = *(const bf16x8*)qpB;
    const bf16x8 qB1 = *(const bf16x8*)(qpB + 32);

    // staging: chunk j (0..7) = rows j*8..j*8+7; lane l -> row j*8+(l>>3),
    // source 16B-chunk (l&7)^(l>>3) (pre-swizzled source, linear LDS dest)
    const int jj0 = w * 2, jj1 = w * 2 + 1;
    const int sr0 = jj0 * 8 + (l >> 3), sr1 = jj1 * 8 + (l >> 3);
    const int sc = ((l & 7) ^ (l >> 3)) * 8;
    const u16* kg0 = K + ((size_t)(b * 1024 + sr0)) * 1024 + h * 64 + sc;
    const u16* kg1 = K + ((size_t)(b * 1024 + sr1)) * 1024 + h * 64 + sc;
    const u16* vg0 = Vt2 + ((size_t)(h * 64 + sr0)) * 8192 + b * 1024 + sc;
    const u16* vg1 = Vt2 + ((size_t)(h * 64 + sr1)) * 8192 + b * 1024 + sc;
    const int lk0 = jj0 * 512 + l * 8, lk1 = jj1 * 512 + l * 8;

#define FSTG(S, kt)                                         \
    gload16(kg0 + (size_t)(kt) * 1024, Ks[S] + lk0);        \
    gload16(kg1 + (size_t)(kt) * 1024, Ks[S] + lk1);        \
    gload16(vg0 + (kt), Vs[S] + lk0);                       \
    gload16(vg1 + (kt), Vs[S] + lk1);

    f32x4 oA[4] = {}, oB[4] = {};
    float mA = 0.f, lA = 0.f, mB = 0.f, lB = 0.f;   // lA/lB per-lane partials
    bf16x4 p0A[4], p0B[4], p1A[4], p1B[4];          // ping-pong P sets (static names)

    FSTG(0, 0) FSTG(1, 64)

#define FITER(T, PCA, PCB, PPA, PPB, VMN, DOPV)                              \
    {                                                                        \
        vm_wait<VMN>();                                                      \
        __builtin_amdgcn_s_barrier();                                        \
        f32x4 sA[4], sB[4];                                                  \
        qk_tile(Ks[(T) & 3], fr, gg, qA0, qA1, qB0, qB1, mA, mB, sA, sB);    \
        if ((T) + 2 <= 15) { FSTG((((T) + 2) & 3), ((T) + 2) * 64) }         \
        if (DOPV) pv_tile(Vs[((T) - 1) & 3], fr, gg, PPA, PPB, oA, oB);      \
        sm_tile(sA, oA, mA, lA, PCA);                                        \
        sm_tile(sB, oB, mB, lB, PCB);                                        \
    }

    FITER(0,  p0A, p0B, p1A, p1B, 4, false)
    FITER(1,  p1A, p1B, p0A, p0B, 4, true)
    FITER(2,  p0A, p0B, p1A, p1B, 4, true)
    FITER(3,  p1A, p1B, p0A, p0B, 4, true)
    FITER(4,  p0A, p0B, p1A, p1B, 4, true)
    FITER(5,  p1A, p1B, p0A, p0B, 4, true)
    FITER(6,  p0A, p0B, p1A, p1B, 4, true)
    FITER(7,  p1A, p1B, p0A, p0B, 4, true)
    FITER(8,  p0A, p0B, p1A, p1B, 4, true)
    FITER(9,  p1A, p1B, p0A, p0B, 4, true)
    FITER(10, p0A, p0B, p1A, p1B, 4, true)
    FITER(11, p1A, p1B, p0A, p0B, 4, true)
    FITER(12, p0A, p0B, p1A, p1B, 4, true)
    FITER(13, p1A, p1B, p0A, p0B, 4, true)
    FITER(14, p0A, p0B, p1A, p1B, 4, true)
    FITER(15, p1A, p1B, p0A, p0B, 0, true)
#undef FITER
#undef FSTG
    // drain: PV of the last tile (slot 15&3 = 3, P = p1 sets)
    pv_tile(Vs[3], fr, gg, p1A, p1B, oA, oB);

    // epilogue: cross-lane lsum reduce (once), then O[t][h*64 + mt*16 + f4 + r]
    lA += __shfl_xor(lA, 16, 64); lA += __shfl_xor(lA, 32, 64);
    lB += __shfl_xor(lB, 16, 64); lB += __shfl_xor(lB, 32, 64);
    const float ivA = 1.0f / lA, ivB = 1.0f / lB;
    u16* opA = O + ((size_t)(b * 1024 + qw + fr)) * 1024 + h * 64;
    u16* opB = opA + 16 * 1024;
#pragma unroll
    for (int mt = 0; mt < 4; ++mt) {
        u16x4 oa, ob;
#pragma unroll
        for (int r = 0; r < 4; ++r) { oa[r] = f2bf(oA[mt][r] * ivA); ob[r] = f2bf(oB[mt][r] * ivB); }
        *(u16x4*)(opA + mt * 16 + f4) = oa;
        *(u16x4*)(opB + mt * 16 + f4) = ob;
    }
}

extern "C" void kernel_launch(void* const* d_in, const int* in_sizes, int n_in,
                              void* d_out, int out_size, void* d_ws, size_t ws_size,
                              hipStream_t stream) {
    (void)in_sizes; (void)n_in; (void)out_size; (void)ws_size;
    const float* hs = (const float*)d_in[0];
    const float* Wq = (const float*)d_in[1];
    const float* bq = (const float*)d_in[2];
    const float* Wk = (const float*)d_in[3];
    const float* bk = (const float*)d_in[4];
    const float* Wv = (const float*)d_in[5];
    const float* bv = (const float*)d_in[6];
    const float* Wo = (const float*)d_in[7];
    const float* bo = (const float*)d_in[8];
    float* out = (float*)d_out;
    char* ws = (char*)d_ws;
    const size_t MB = 1024ull * 1024ull;
    u16* Xb  = (u16*)(ws);            // 16 MB (dead after V^T GEMM; reused as attn output Ob)
    u16* Wqt = (u16*)(ws + 16 * MB);  // 2 MB each; Wqt+Wkt adjacent => stacked [2048][1024]
    u16* Wkt = (u16*)(ws + 18 * MB);
    u16* Wvt = (u16*)(ws + 20 * MB);
    u16* Wot = (u16*)(ws + 22 * MB);
    u16* Qb  = (u16*)(ws + 24 * MB);  // 16 MB
    u16* Kb  = (u16*)(ws + 40 * MB);  // 16 MB
    u16* Vt2 = (u16*)(ws + 56 * MB);  // 16 MB: V^T[n][t-permuted], ld=8192 -> 72 MB total
    u16* Ob  = Xb;

    // HD^-0.5 * log2(e) folded into Wq and bq (softmax runs in log2 domain)
    const float SCALE_Q = 0.125f * 1.4426950408889634f;

    k_cvt<<<dim3(8192), dim3(256), 0, stream>>>(hs, Xb);
    k_wtrans4<<<dim3(32, 32, 4), dim3(256), 0, stream>>>(Wq, Wk, Wv, Wo, Wqt, Wkt, Wvt, Wot, SCALE_Q);
    // fused Q+K projection: M=8192, N=2048 over stacked [Wqt;Wkt]; 32x8 = 256 blocks (1/CU)
    k_g256<256><<<dim3(256), dim3(512), 0, stream>>>(Xb, Wqt, bq, bk, SCALE_Q,
                                                     Qb, Kb, nullptr, 1024, 0, 8, 1);
    // V^T = Wv^T * X^T (k-permuted cols): A = Wvt (M=1024), Bt = Xb (N=8192); 4x64 blocks
    k_g256<128><<<dim3(256), dim3(512), 0, stream>>>(Wvt, Xb, bv, nullptr, 1.f,
                                                     Vt2, nullptr, nullptr, 8192, 1, 64, 2);
    k_flash<<<dim3(1024), dim3(256), 0, stream>>>(Qb, Kb, Vt2, Ob);
    // output projection: M=8192, N=1024, f32 out; 32x8 = 256 blocks
    k_g256<128><<<dim3(256), dim3(512), 0, stream>>>(Ob, Wot, bo, nullptr, 1.f,
                                                     nullptr, nullptr, out, 1024, 0, 8, 0);
}